// Round 11
// baseline (504.198 us; speedup 1.0000x reference)
//
#include <hip/hip_runtime.h>
#include <hip/hip_bf16.h>

#define N_NODES 50000
#define NE      800000
#define NETOT   (NE + N_NODES)
#define NEG     0.2f
#define NBUCK   196      // ceil(50000/256) dst buckets
#define NSEG    64       // sub-counters per bucket (atomic-contention fix, r10-proven)
#define SEGCAP  128      // mean 63.8 + 8 sigma
#define NCTR    (NBUCK * NSEG)

typedef unsigned short u16;
typedef unsigned int   u32;
typedef __attribute__((ext_vector_type(8))) short bf16x8;
typedef __attribute__((ext_vector_type(4))) float f32x4;

__device__ __forceinline__ float b2f(u16 v) {
    union { float f; u32 u; } c; c.u = ((u32)v) << 16; return c.f;
}
__device__ __forceinline__ u16 f2b(float f) {
    union { float f; u32 u; } c; c.f = f;
    u32 r = c.u + 0x7FFF + ((c.u >> 16) & 1);
    return (u16)(r >> 16);
}
__device__ __forceinline__ float ldf(const void* p, int i, int fmt) {
    return fmt ? b2f(((const u16*)p)[i]) : ((const float*)p)[i];
}
__device__ __forceinline__ float wlo(u32 w) { return __uint_as_float(w << 16); }
__device__ __forceinline__ float whi(u32 w) { return __uint_as_float(w & 0xffff0000u); }

// ---- fused init: format probes + i64 probe + bcnt zero (1 kernel, grid 49) ----
__global__ void init_all(const u32* __restrict__ xw, const u32* __restrict__ w0,
                         const int* __restrict__ ei,
                         int* __restrict__ flag, int* __restrict__ bcnt) {
    int g = blockIdx.x * 256 + threadIdx.x;
    if (g < NCTR) bcnt[g] = 0;
    if (blockIdx.x == 0) {
        int wv = threadIdx.x >> 6, l = threadIdx.x & 63;
        if (wv == 0) {          // x storage format -> flag[0]; flag[1]=0
            u32 v = xw[l * 50000 + 1];
            u32 e = (v >> 7) & 0xFF;
            unsigned long long m = __ballot(e >= 100 && e <= 140);
            if (l == 0) { flag[0] = (__popcll(m) >= 48) ? 1 : 0; flag[1] = 0; }
        } else if (wv == 1) {   // params family format -> flag[3]
            u32 v = w0[l * 128 + 1];
            u32 e = (v >> 7) & 0xFF;
            unsigned long long m = __ballot(e >= 100 && e <= 140);
            if (l == 0) flag[3] = (__popcll(m) >= 48) ? 1 : 0;
        } else if (wv == 2) {   // edge_index int64? -> flag[2]
            int v = ei[(l * 25000) | 1];
            unsigned long long nz = __ballot(v != 0);
            if (l == 0) flag[2] = (nz == 0ULL) ? 1 : 0;
        }
    }
}

// ---------------- binned CSR build (segmented counters) ----------------
__global__ void bin_a(const int* __restrict__ ei, const int* __restrict__ flag,
                      int* __restrict__ bcnt, uint2* __restrict__ pairs) {
    int e = blockIdx.x * 256 + threadIdx.x;
    if (e >= NE) return;
    int f = flag[2];
    int s, d;
    if (f) { s = ei[2 * e]; d = ei[2 * (NE + e)]; }
    else   { s = ei[e];     d = ei[NE + e]; }
    int idx = (d >> 8) * NSEG + (blockIdx.x & (NSEG - 1));
    int pos = atomicAdd(&bcnt[idx], 1);
    if (pos < SEGCAP) pairs[(size_t)idx * SEGCAP + pos] = make_uint2((u32)s, (u32)d);
}

__global__ void bucket_scan(const int* __restrict__ bcnt, int* __restrict__ bbase,
                            int* __restrict__ indptr) {
    __shared__ int sh[256];
    int tid = threadIdx.x;
    int tot = 0;
    if (tid < NBUCK) {
        int nb0 = tid << 8;
        int nodes = min(256, N_NODES - nb0);
        int edges = 0;
        for (int seg = 0; seg < NSEG; ++seg)
            edges += min(bcnt[tid * NSEG + seg], SEGCAP);
        tot = edges + nodes;
    }
    sh[tid] = tot; __syncthreads();
    for (int off = 1; off < 256; off <<= 1) {
        int u = (tid >= off) ? sh[tid - off] : 0;
        __syncthreads();
        sh[tid] += u;
        __syncthreads();
    }
    if (tid < NBUCK) bbase[tid] = sh[tid] - tot;
    if (tid == 0) indptr[N_NODES] = sh[NBUCK - 1];
}

__global__ __launch_bounds__(256) void bin_b(const uint2* __restrict__ pairs,
        const int* __restrict__ bcnt, const int* __restrict__ bbase,
        int* __restrict__ indptr, int* __restrict__ srcs) {
    __shared__ int cnt[256];
    __shared__ int scn[256];
    __shared__ int msh[NSEG];
    int b = blockIdx.x, tid = threadIdx.x;
    int nb0 = b << 8;
    int nodesHere = min(256, N_NODES - nb0);
    if (tid < NSEG) msh[tid] = min(bcnt[b * NSEG + tid], SEGCAP);
    cnt[tid] = (tid < nodesHere) ? 1 : 0;   // self loop
    __syncthreads();
    const uint2* bp = pairs + (size_t)b * NSEG * SEGCAP;
    for (int t = tid; t < NSEG * SEGCAP; t += 256) {
        int seg = t >> 7, i = t & (SEGCAP - 1);
        if (i < msh[seg]) {
            int d = (int)bp[t].y;
            atomicAdd(&cnt[d - nb0], 1);
        }
    }
    __syncthreads();
    int v = cnt[tid];
    scn[tid] = v; __syncthreads();
    for (int off = 1; off < 256; off <<= 1) {
        int u = (tid >= off) ? scn[tid - off] : 0;
        __syncthreads();
        scn[tid] += u;
        __syncthreads();
    }
    int myoff = bbase[b] + scn[tid] - v;
    if (tid < nodesHere) indptr[nb0 + tid] = myoff;
    __syncthreads();
    cnt[tid] = myoff;
    __syncthreads();
    if (tid < nodesHere) {
        int pos = atomicAdd(&cnt[tid], 1);
        srcs[pos] = nb0 + tid;
    }
    for (int t = tid; t < NSEG * SEGCAP; t += 256) {
        int seg = t >> 7, i = t & (SEGCAP - 1);
        if (i < msh[seg]) {
            uint2 p = bp[t];
            int pos = atomicAdd(&cnt[(int)p.y - nb0], 1);
            srcs[pos] = (int)p.x;
        }
    }
}

// ------------- MFMA transform GEMM with optional fused input-norm -------------
#define LDP 136
__global__ __launch_bounds__(256) void gemm_xf(const void* __restrict__ inp,
        const int* __restrict__ fin, const int* __restrict__ fw,
        const void* __restrict__ Wl, const void* __restrict__ bl,
        const void* __restrict__ Wr, const void* __restrict__ br,
        const float* __restrict__ nscale, const float* __restrict__ nshift,
        u16* __restrict__ XL, u16* __restrict__ XR) {
    __shared__ u16 As16[64 * LDP];
    __shared__ u16 Bs16[64 * LDP];
    __shared__ float Sc[128], Sh[128];
    int fi = fin[0], fb = fw[0];
    int by = blockIdx.y;
    const void* W  = (by < 2) ? Wl : Wr;
    const void* bi = (by < 2) ? bl : br;
    u16* dst       = (by < 2) ? XL : XR;
    int jb = (by & 1) * 64;
    int n0 = blockIdx.x * 64;
    int tid = threadIdx.x;
    bool donorm = (nscale != nullptr);
    if (donorm) {
        if (tid < 128) { Sc[tid] = nscale[tid]; Sh[tid] = nshift[tid]; }
        __syncthreads();
    }
    if (fi) {
        for (int t = tid; t < 64 * 16; t += 256) {
            int node = t >> 4, c8 = (t & 15) << 3;
            int n = n0 + node;
            bf16x8 v = {0,0,0,0,0,0,0,0};
            if (n < N_NODES) v = *(const bf16x8*)((const u16*)inp + (size_t)n * 128 + c8);
            *(bf16x8*)&As16[node * LDP + c8] = v;
        }
    } else {
        for (int t = tid; t < 64 * 32; t += 256) {
            int node = t >> 5, c4 = (t & 31) << 2;
            int n = n0 + node;
            float4 v = {0.f, 0.f, 0.f, 0.f};
            if (n < N_NODES) v = *(const float4*)((const float*)inp + (size_t)n * 128 + c4);
            if (donorm) {
                v.x = fmaxf(v.x * Sc[c4]     + Sh[c4],     0.f);
                v.y = fmaxf(v.y * Sc[c4 + 1] + Sh[c4 + 1], 0.f);
                v.z = fmaxf(v.z * Sc[c4 + 2] + Sh[c4 + 2], 0.f);
                v.w = fmaxf(v.w * Sc[c4 + 3] + Sh[c4 + 3], 0.f);
            }
            ushort4 h;
            h.x = f2b(v.x); h.y = f2b(v.y); h.z = f2b(v.z); h.w = f2b(v.w);
            *(ushort4*)&As16[node * LDP + c4] = h;
        }
    }
    if (fb) {
        for (int t = tid; t < 128 * 8; t += 256) {
            int k = t >> 3, j8 = (t & 7) << 3;
            bf16x8 v = *(const bf16x8*)((const u16*)W + k * 128 + jb + j8);
            #pragma unroll
            for (int q = 0; q < 8; ++q) Bs16[(j8 + q) * LDP + k] = (u16)v[q];
        }
    } else {
        for (int t = tid; t < 128 * 16; t += 256) {
            int k = t >> 4, j4 = (t & 15) << 2;
            float4 v = *(const float4*)((const float*)W + k * 128 + jb + j4);
            Bs16[(j4 + 0) * LDP + k] = f2b(v.x);
            Bs16[(j4 + 1) * LDP + k] = f2b(v.y);
            Bs16[(j4 + 2) * LDP + k] = f2b(v.z);
            Bs16[(j4 + 3) * LDP + k] = f2b(v.w);
        }
    }
    __syncthreads();

    int wv = tid >> 6, lane = tid & 63;
    int quad = lane >> 4, r = lane & 15;
    int m0 = wv * 16;
    f32x4 acc[4] = {{0.f,0.f,0.f,0.f},{0.f,0.f,0.f,0.f},
                    {0.f,0.f,0.f,0.f},{0.f,0.f,0.f,0.f}};
    #pragma unroll
    for (int ks = 0; ks < 4; ++ks) {
        int ko = ks * 32 + quad * 8;
        bf16x8 af = *(const bf16x8*)&As16[(m0 + r) * LDP + ko];
        #pragma unroll
        for (int t = 0; t < 4; ++t) {
            bf16x8 bfr = *(const bf16x8*)&Bs16[(t * 16 + r) * LDP + ko];
            acc[t] = __builtin_amdgcn_mfma_f32_16x16x32_bf16(af, bfr, acc[t], 0, 0, 0);
        }
    }
    #pragma unroll
    for (int t = 0; t < 4; ++t) {
        int j = jb + t * 16 + r;
        float bj = ldf(bi, j, fb);
        #pragma unroll
        for (int reg = 0; reg < 4; ++reg) {
            int node = n0 + m0 + quad * 4 + reg;
            if (node < N_NODES) dst[node * 128 + j] = f2b(acc[t][reg] + bj);
        }
    }
}

// ------ per-dst softmax aggregation: quarter-wave per edge (4-edge MLP) ------
// 2 waves/block, 1 node/wave. Within a wave: eh = lane>>4 processes edge
// (beg+4*it+eh); lane q = lane&15 owns channels 8q..8q+7 (one 16B uint4 load).
// q<8 -> head0, q>=8 -> head1; per-head score butterfly = xor 1,2,4.
__global__ __launch_bounds__(128) void agg_kernel(const uint4* __restrict__ XL4,
        const uint4* __restrict__ XR4, const void* __restrict__ att,
        const int* __restrict__ fmt,
        const int* __restrict__ indptr, const int* __restrict__ srcs,
        float4* __restrict__ OUT4) {
    int wv = threadIdx.x >> 6;
    int lane = threadIdx.x & 63;
    int n = blockIdx.x * 2 + wv;
    if (n >= N_NODES) return;
    int eh = lane >> 4, q = lane & 15;
    int fb = fmt[0];
    uint4 xr = XR4[(size_t)n * 16 + q];
    float xr0 = wlo(xr.x), xr1 = whi(xr.x), xr2 = wlo(xr.y), xr3 = whi(xr.y);
    float xr4 = wlo(xr.z), xr5 = whi(xr.z), xr6 = wlo(xr.w), xr7 = whi(xr.w);
    float a0 = ldf(att, 8 * q,     fb), a1 = ldf(att, 8 * q + 1, fb);
    float a2 = ldf(att, 8 * q + 2, fb), a3 = ldf(att, 8 * q + 3, fb);
    float a4 = ldf(att, 8 * q + 4, fb), a5 = ldf(att, 8 * q + 5, fb);
    float a6 = ldf(att, 8 * q + 6, fb), a7 = ldf(att, 8 * q + 7, fb);
    int beg = indptr[n], end = indptr[n + 1];
    float c0 = 0.f, c1 = 0.f, c2 = 0.f, c3 = 0.f;
    float c4 = 0.f, c5 = 0.f, c6 = 0.f, c7 = 0.f, dsum = 0.f;
    int nit = (end - beg + 3) >> 2;
    for (int it = 0; it < nit; ++it) {
        int i = beg + 4 * it + eh;
        bool valid = (i < end);
        int s = valid ? srcs[i] : 0;
        uint4 xl = XL4[(size_t)s * 16 + q];
        float x0 = wlo(xl.x), x1 = whi(xl.x), x2 = wlo(xl.y), x3 = whi(xl.y);
        float x4 = wlo(xl.z), x5 = whi(xl.z), x6 = wlo(xl.w), x7 = whi(xl.w);
        float t0 = x0 + xr0; t0 = fmaxf(t0, 0.f) + NEG * fminf(t0, 0.f);
        float t1 = x1 + xr1; t1 = fmaxf(t1, 0.f) + NEG * fminf(t1, 0.f);
        float t2 = x2 + xr2; t2 = fmaxf(t2, 0.f) + NEG * fminf(t2, 0.f);
        float t3 = x3 + xr3; t3 = fmaxf(t3, 0.f) + NEG * fminf(t3, 0.f);
        float t4 = x4 + xr4; t4 = fmaxf(t4, 0.f) + NEG * fminf(t4, 0.f);
        float t5 = x5 + xr5; t5 = fmaxf(t5, 0.f) + NEG * fminf(t5, 0.f);
        float t6 = x6 + xr6; t6 = fmaxf(t6, 0.f) + NEG * fminf(t6, 0.f);
        float t7 = x7 + xr7; t7 = fmaxf(t7, 0.f) + NEG * fminf(t7, 0.f);
        float p = t0 * a0;
        p = fmaf(t1, a1, p); p = fmaf(t2, a2, p); p = fmaf(t3, a3, p);
        p = fmaf(t4, a4, p); p = fmaf(t5, a5, p); p = fmaf(t6, a6, p);
        p = fmaf(t7, a7, p);
        p += __shfl_xor(p, 1);
        p += __shfl_xor(p, 2);
        p += __shfl_xor(p, 4);          // per-head sum within 8-lane group
        float w = valid ? __expf(fminf(p, 60.f)) : 0.f;
        c0 = fmaf(w, x0, c0); c1 = fmaf(w, x1, c1);
        c2 = fmaf(w, x2, c2); c3 = fmaf(w, x3, c3);
        c4 = fmaf(w, x4, c4); c5 = fmaf(w, x5, c5);
        c6 = fmaf(w, x6, c6); c7 = fmaf(w, x7, c7);
        dsum += w;
    }
    // merge the 4 edge-subsets (lanes q, 16+q, 32+q, 48+q hold same channels)
    c0 += __shfl_xor(c0, 16); c1 += __shfl_xor(c1, 16);
    c2 += __shfl_xor(c2, 16); c3 += __shfl_xor(c3, 16);
    c4 += __shfl_xor(c4, 16); c5 += __shfl_xor(c5, 16);
    c6 += __shfl_xor(c6, 16); c7 += __shfl_xor(c7, 16);
    dsum += __shfl_xor(dsum, 16);
    c0 += __shfl_xor(c0, 32); c1 += __shfl_xor(c1, 32);
    c2 += __shfl_xor(c2, 32); c3 += __shfl_xor(c3, 32);
    c4 += __shfl_xor(c4, 32); c5 += __shfl_xor(c5, 32);
    c6 += __shfl_xor(c6, 32); c7 += __shfl_xor(c7, 32);
    dsum += __shfl_xor(dsum, 32);
    if (eh == 0) {
        float inv = 1.f / (dsum + 1e-16f);
        float4 oA, oB;
        oA.x = c0 * inv; oA.y = c1 * inv; oA.z = c2 * inv; oA.w = c3 * inv;
        oB.x = c4 * inv; oB.y = c5 * inv; oB.z = c6 * inv; oB.w = c7 * inv;
        OUT4[(size_t)n * 32 + 2 * q]     = oA;
        OUT4[(size_t)n * 32 + 2 * q + 1] = oB;
    }
}

// ---------------- GraphNorm stats: per-block partials (no atomics) ----------
__global__ __launch_bounds__(256) void colstats(const float* __restrict__ OUT,
        const void* __restrict__ bias, const int* __restrict__ fmt,
        float* __restrict__ Sp1, float* __restrict__ Sp2) {
    __shared__ float sh1[256], sh2[256];
    int tid = threadIdx.x;
    int c = tid & 127, half = tid >> 7;
    float bf = ldf(bias, c, fmt[0]);
    float s1 = 0.f, s2 = 0.f;
    for (int r = blockIdx.x * 2 + half; r < N_NODES; r += gridDim.x * 2) {
        float t = OUT[r * 128 + c] + bf;
        s1 += t; s2 += t * t;
    }
    sh1[tid] = s1; sh2[tid] = s2; __syncthreads();
    if (tid < 128) {
        Sp1[blockIdx.x * 128 + tid] = sh1[tid] + sh1[tid + 128];
        Sp2[blockIdx.x * 128 + tid] = sh2[tid] + sh2[tid + 128];
    }
}

__global__ void finalize_norm(const float* __restrict__ Sp1, const float* __restrict__ Sp2,
        const void* __restrict__ gamma, const void* __restrict__ beta,
        const void* __restrict__ msc, const void* __restrict__ bias,
        const int* __restrict__ fmt,
        float* __restrict__ scaleA, float* __restrict__ shiftB) {
    int c = threadIdx.x;
    if (c >= 128) return;
    float s1 = 0.f, s2 = 0.f;
    for (int b = 0; b < 256; ++b) {
        s1 += Sp1[b * 128 + c];
        s2 += Sp2[b * 128 + c];
    }
    int fb = fmt[0];
    const float invN = 1.f / (float)N_NODES;
    float mean = s1 * invN;
    float ex2  = s2 * invN;
    float ms = ldf(msc, c, fb);
    float var = ex2 - 2.f * ms * mean * mean + ms * ms * mean * mean;
    float rstd = rsqrtf(var + 1e-5f);
    float A = ldf(gamma, c, fb) * rstd;
    scaleA[c] = A;
    shiftB[c] = ldf(beta, c, fb) - A * (ms * mean - ldf(bias, c, fb));
}

// ---------------- fused MLP head with fused input norm+relu, fp32 out ---------
__global__ __launch_bounds__(256) void mlp_kernel(const float* __restrict__ H,
        const void* __restrict__ w1, const void* __restrict__ b1,
        const void* __restrict__ w2, const void* __restrict__ b2,
        const float* __restrict__ nscale, const float* __restrict__ nshift,
        const int* __restrict__ fmt,
        float* __restrict__ out) {
    __shared__ float W1s[128 * 64];
    __shared__ float W2s[128];
    __shared__ float b1s[64];
    __shared__ float Sc[128], Sh[128];
    int tid = threadIdx.x;
    int fb = fmt[0];
    if (fb) {
        for (int t = tid; t < 128 * 8; t += 256) {
            int row8 = t << 3;
            bf16x8 v = *(const bf16x8*)((const u16*)w1 + row8);
            #pragma unroll
            for (int q = 0; q < 8; ++q) W1s[row8 + q] = b2f((u16)v[q]);
        }
    } else {
        for (int t = tid; t < 128 * 64; t += 256) W1s[t] = ((const float*)w1)[t];
    }
    if (tid < 128) { W2s[tid] = ldf(w2, tid, fb); Sc[tid] = nscale[tid]; Sh[tid] = nshift[tid]; }
    if (tid < 64)  b1s[tid] = ldf(b1, tid, fb);
    __syncthreads();
    int n = blockIdx.x * 256 + tid;
    if (n >= N_NODES) return;
    float z[64];
    #pragma unroll
    for (int j = 0; j < 64; j++) z[j] = b1s[j];
    for (int kb = 0; kb < 128; kb += 16) {
        float h[16];
        #pragma unroll
        for (int t = 0; t < 4; t++) {
            float4 v = *(const float4*)&H[n * 128 + kb + t * 4];
            int c = kb + t * 4;
            h[4 * t]     = fmaxf(v.x * Sc[c]     + Sh[c],     0.f);
            h[4 * t + 1] = fmaxf(v.y * Sc[c + 1] + Sh[c + 1], 0.f);
            h[4 * t + 2] = fmaxf(v.z * Sc[c + 2] + Sh[c + 2], 0.f);
            h[4 * t + 3] = fmaxf(v.w * Sc[c + 3] + Sh[c + 3], 0.f);
        }
        #pragma unroll
        for (int i = 0; i < 16; i++) {
            float hv = h[i];
            const float* wrow = &W1s[(kb + i) * 64];
            #pragma unroll
            for (int j = 0; j < 64; j += 4) {
                const float4 w = *(const float4*)&wrow[j];
                z[j]     += hv * w.x;
                z[j + 1] += hv * w.y;
                z[j + 2] += hv * w.z;
                z[j + 3] += hv * w.w;
            }
        }
    }
    float o0 = ldf(b2, 0, fb), o1 = ldf(b2, 1, fb);
    #pragma unroll
    for (int j = 0; j < 64; j++) {
        float zr = fmaxf(z[j], 0.f);
        o0 += zr * W2s[j * 2];
        o1 += zr * W2s[j * 2 + 1];
    }
    if (o0 != o0) o0 = 12345.f;   // NaN canary
    if (o1 != o1) o1 = 12345.f;
    float2 o; o.x = o0; o.y = o1;
    ((float2*)out)[n] = o;
}

// ---------------- launch ----------------
extern "C" void kernel_launch(void* const* d_in, const int* in_sizes, int n_in,
                              void* d_out, int out_size, void* d_ws, size_t ws_size,
                              hipStream_t stream) {
    (void)in_sizes; (void)n_in; (void)out_size; (void)ws_size;
    const void* x    = d_in[0];
    const int*  ei   = (const int*)d_in[1];
    const void* Wl0  = d_in[2];
    const void* bl0  = d_in[3];
    const void* Wr0  = d_in[4];
    const void* br0  = d_in[5];
    const void* att0 = d_in[6];
    const void* bias0= d_in[7];
    const void* Wl1  = d_in[8];
    const void* bl1  = d_in[9];
    const void* Wr1  = d_in[10];
    const void* br1  = d_in[11];
    const void* att1 = d_in[12];
    const void* bias1= d_in[13];
    const void* g0   = d_in[14];
    const void* be0  = d_in[15];
    const void* ms0  = d_in[16];
    const void* g1   = d_in[17];
    const void* be1  = d_in[18];
    const void* ms1  = d_in[19];
    const void* W1   = d_in[20];
    const void* b1   = d_in[21];
    const void* W2   = d_in[22];
    const void* b2   = d_in[23];

    char* ws = (char*)d_ws;
    const size_t NF2 = (size_t)N_NODES * 128 * 2;
    const size_t NF4 = (size_t)N_NODES * 128 * 4;
    u16*   XLb = (u16*)(ws);
    u16*   XRb = (u16*)(ws + NF2);
    float* B2  = (float*)(ws + 2 * NF2);
    uint2* pairs = (uint2*)B2;            // 12.85 MB, aliased (dead before agg writes B2)
    char* small = ws + 2 * NF2 + NF4;     // 51.2 MB offset
    float* scaleA = (float*)(small + 1024);
    float* shiftB = (float*)(small + 1536);
    int*   flag   = (int*)(small + 2048);  // [0]=x bf16 [1]=0 [2]=i64 [3]=params bf16
    int*   bbase  = (int*)(small + 2112);  // 196 ints
    float* Sp1    = (float*)(small + 4096);            // 256*128 f = 128 KB
    float* Sp2    = (float*)(small + 4096 + 131072);   // 128 KB
    int*   bcnt   = (int*)(small + 4096 + 262144);     // 12544 ints
    int*   indptr = (int*)(small + 4096 + 262144 + 50176);
    int*   srcs   = indptr + (N_NODES + 64);
    // footprint ~55.1 MB (proven budget)

    const int* fX   = &flag[0];
    const int* fFP  = &flag[1];
    const int* fPar = &flag[3];

    // fused probes + counter zeroing
    init_all<<<(NCTR + 255) / 256, 256, 0, stream>>>((const u32*)x, (const u32*)Wl0,
                                                     ei, flag, bcnt);
    // binned CSR build
    bin_a<<<(NE + 255) / 256, 256, 0, stream>>>(ei, flag, bcnt, pairs);
    bucket_scan<<<1, 256, 0, stream>>>(bcnt, bbase, indptr);
    bin_b<<<NBUCK, 256, 0, stream>>>(pairs, bcnt, bbase, indptr, srcs);

    dim3 ggemm((N_NODES + 63) / 64, 4);

    for (int layer = 0; layer < 2; ++layer) {
        const void* Wl = layer ? Wl1 : Wl0;  const void* bl = layer ? bl1 : bl0;
        const void* Wr = layer ? Wr1 : Wr0;  const void* br = layer ? br1 : br0;
        const void* at = layer ? att1 : att0;
        const void* bi = layer ? bias1 : bias0;
        const void* gm = layer ? g1 : g0;    const void* bt = layer ? be1 : be0;
        const void* mS = layer ? ms1 : ms0;
        const void* inp = layer ? (const void*)B2 : x;
        const int* fin  = layer ? fFP : fX;
        const float* ns = layer ? scaleA : nullptr;
        const float* nh = layer ? shiftB : nullptr;

        gemm_xf<<<ggemm, 256, 0, stream>>>(inp, fin, fPar, Wl, bl, Wr, br, ns, nh,
                                           XLb, XRb);
        agg_kernel<<<(N_NODES + 1) / 2, 128, 0, stream>>>((const uint4*)XLb,
                                                          (const uint4*)XRb,
                                                          at, fPar, indptr, srcs,
                                                          (float4*)B2);
        colstats<<<256, 256, 0, stream>>>(B2, bi, fPar, Sp1, Sp2);
        finalize_norm<<<1, 128, 0, stream>>>(Sp1, Sp2, gm, bt, mS, bi, fPar,
                                             scaleA, shiftB);
    }

    mlp_kernel<<<(N_NODES + 255) / 256, 256, 0, stream>>>(B2, W1, b1, W2, b2,
                                                          scaleA, shiftB, fPar,
                                                          (float*)d_out);
}

// Round 13
// 487.008 us; speedup vs baseline: 1.0353x; 1.0353x over previous
//
#include <hip/hip_runtime.h>
#include <hip/hip_bf16.h>

#define N_NODES 50000
#define NE      800000
#define NETOT   (NE + N_NODES)
#define NEG     0.2f
#define NBUCK   196      // ceil(50000/256) dst buckets
#define NSEG    64       // sub-counters per bucket (atomic-contention fix, r10-proven)
#define SEGCAP  128      // mean 63.8 + 8 sigma
#define NCTR    (NBUCK * NSEG)

typedef unsigned short u16;
typedef unsigned int   u32;
typedef __attribute__((ext_vector_type(8))) short bf16x8;
typedef __attribute__((ext_vector_type(4))) float f32x4;

__device__ __forceinline__ float b2f(u16 v) {
    union { float f; u32 u; } c; c.u = ((u32)v) << 16; return c.f;
}
__device__ __forceinline__ u16 f2b(float f) {
    union { float f; u32 u; } c; c.f = f;
    u32 r = c.u + 0x7FFF + ((c.u >> 16) & 1);
    return (u16)(r >> 16);
}
__device__ __forceinline__ float ldf(const void* p, int i, int fmt) {
    return fmt ? b2f(((const u16*)p)[i]) : ((const float*)p)[i];
}

// ---- fused init: format probes + i64 probe + bcnt zero ----
__global__ void init_all(const u32* __restrict__ xw, const u32* __restrict__ w0,
                         const int* __restrict__ ei,
                         int* __restrict__ flag, int* __restrict__ bcnt) {
    int g = blockIdx.x * 256 + threadIdx.x;
    if (g < NCTR) bcnt[g] = 0;
    if (blockIdx.x == 0) {
        int wv = threadIdx.x >> 6, l = threadIdx.x & 63;
        if (wv == 0) {          // x storage format -> flag[0]; flag[1]=0
            u32 v = xw[l * 50000 + 1];
            u32 e = (v >> 7) & 0xFF;
            unsigned long long m = __ballot(e >= 100 && e <= 140);
            if (l == 0) { flag[0] = (__popcll(m) >= 48) ? 1 : 0; flag[1] = 0; }
        } else if (wv == 1) {   // params family format -> flag[3]
            u32 v = w0[l * 128 + 1];
            u32 e = (v >> 7) & 0xFF;
            unsigned long long m = __ballot(e >= 100 && e <= 140);
            if (l == 0) flag[3] = (__popcll(m) >= 48) ? 1 : 0;
        } else if (wv == 2) {   // edge_index int64? -> flag[2]
            int v = ei[(l * 25000) | 1];
            unsigned long long nz = __ballot(v != 0);
            if (l == 0) flag[2] = (nz == 0ULL) ? 1 : 0;
        }
    }
}

// ---------------- binned CSR build (segmented counters) ----------------
__global__ void bin_a(const int* __restrict__ ei, const int* __restrict__ flag,
                      int* __restrict__ bcnt, uint2* __restrict__ pairs) {
    int e = blockIdx.x * 256 + threadIdx.x;
    if (e >= NE) return;
    int f = flag[2];
    int s, d;
    if (f) { s = ei[2 * e]; d = ei[2 * (NE + e)]; }
    else   { s = ei[e];     d = ei[NE + e]; }
    int idx = (d >> 8) * NSEG + (blockIdx.x & (NSEG - 1));
    int pos = atomicAdd(&bcnt[idx], 1);
    if (pos < SEGCAP) pairs[(size_t)idx * SEGCAP + pos] = make_uint2((u32)s, (u32)d);
}

__global__ void bucket_scan(const int* __restrict__ bcnt, int* __restrict__ bbase,
                            int* __restrict__ indptr) {
    __shared__ int sh[256];
    int tid = threadIdx.x;
    int tot = 0;
    if (tid < NBUCK) {
        int nb0 = tid << 8;
        int nodes = min(256, N_NODES - nb0);
        int edges = 0;
        for (int seg = 0; seg < NSEG; ++seg)
            edges += min(bcnt[tid * NSEG + seg], SEGCAP);
        tot = edges + nodes;
    }
    sh[tid] = tot; __syncthreads();
    for (int off = 1; off < 256; off <<= 1) {
        int u = (tid >= off) ? sh[tid - off] : 0;
        __syncthreads();
        sh[tid] += u;
        __syncthreads();
    }
    if (tid < NBUCK) bbase[tid] = sh[tid] - tot;
    if (tid == 0) indptr[N_NODES] = sh[NBUCK - 1];
}

__global__ __launch_bounds__(256) void bin_b(const uint2* __restrict__ pairs,
        const int* __restrict__ bcnt, const int* __restrict__ bbase,
        int* __restrict__ indptr, int* __restrict__ srcs) {
    __shared__ int cnt[256];
    __shared__ int scn[256];
    __shared__ int msh[NSEG];
    int b = blockIdx.x, tid = threadIdx.x;
    int nb0 = b << 8;
    int nodesHere = min(256, N_NODES - nb0);
    if (tid < NSEG) msh[tid] = min(bcnt[b * NSEG + tid], SEGCAP);
    cnt[tid] = (tid < nodesHere) ? 1 : 0;   // self loop
    __syncthreads();
    const uint2* bp = pairs + (size_t)b * NSEG * SEGCAP;
    for (int t = tid; t < NSEG * SEGCAP; t += 256) {
        int seg = t >> 7, i = t & (SEGCAP - 1);
        if (i < msh[seg]) {
            int d = (int)bp[t].y;
            atomicAdd(&cnt[d - nb0], 1);
        }
    }
    __syncthreads();
    int v = cnt[tid];
    scn[tid] = v; __syncthreads();
    for (int off = 1; off < 256; off <<= 1) {
        int u = (tid >= off) ? scn[tid - off] : 0;
        __syncthreads();
        scn[tid] += u;
        __syncthreads();
    }
    int myoff = bbase[b] + scn[tid] - v;
    if (tid < nodesHere) indptr[nb0 + tid] = myoff;
    __syncthreads();
    cnt[tid] = myoff;
    __syncthreads();
    if (tid < nodesHere) {
        int pos = atomicAdd(&cnt[tid], 1);
        srcs[pos] = nb0 + tid;
    }
    for (int t = tid; t < NSEG * SEGCAP; t += 256) {
        int seg = t >> 7, i = t & (SEGCAP - 1);
        if (i < msh[seg]) {
            uint2 p = bp[t];
            int pos = atomicAdd(&cnt[(int)p.y - nb0], 1);
            srcs[pos] = (int)p.x;
        }
    }
}

// ------------- MFMA transform GEMM v3: grid.y=2, LDS-transposed epilogue ------
// by: 0 -> XL = in@Wl+bl, 1 -> XR = in@Wr+br (all 128 output columns per block)
#define LDP 136
__global__ __launch_bounds__(256) void gemm_xf(const void* __restrict__ inp,
        const int* __restrict__ fin, const int* __restrict__ fw,
        const void* __restrict__ Wl, const void* __restrict__ bl,
        const void* __restrict__ Wr, const void* __restrict__ br,
        const float* __restrict__ nscale, const float* __restrict__ nshift,
        u16* __restrict__ XL, u16* __restrict__ XR) {
    __shared__ u16 As16[64 * LDP];    // A: [64 nodes][128 k]  (reused for output)
    __shared__ u16 Bs16[128 * LDP];   // B^T: [128 j][128 k]
    __shared__ float Sc[128], Sh[128];
    int fi = fin[0], fb = fw[0];
    int by = blockIdx.y;
    const void* W  = by ? Wr : Wl;
    const void* bi = by ? br : bl;
    u16* dst       = by ? XR : XL;
    int n0 = blockIdx.x * 64;
    int tid = threadIdx.x;
    bool donorm = (nscale != nullptr);
    if (donorm) {
        if (tid < 128) { Sc[tid] = nscale[tid]; Sh[tid] = nshift[tid]; }
        __syncthreads();
    }
    // stage A [64 nodes][128 k]
    if (fi) {
        for (int t = tid; t < 64 * 16; t += 256) {
            int node = t >> 4, c8 = (t & 15) << 3;
            int n = n0 + node;
            bf16x8 v = {0,0,0,0,0,0,0,0};
            if (n < N_NODES) v = *(const bf16x8*)((const u16*)inp + (size_t)n * 128 + c8);
            *(bf16x8*)&As16[node * LDP + c8] = v;
        }
    } else {
        for (int t = tid; t < 64 * 32; t += 256) {
            int node = t >> 5, c4 = (t & 31) << 2;
            int n = n0 + node;
            float4 v = {0.f, 0.f, 0.f, 0.f};
            if (n < N_NODES) v = *(const float4*)((const float*)inp + (size_t)n * 128 + c4);
            if (donorm) {
                v.x = fmaxf(v.x * Sc[c4]     + Sh[c4],     0.f);
                v.y = fmaxf(v.y * Sc[c4 + 1] + Sh[c4 + 1], 0.f);
                v.z = fmaxf(v.z * Sc[c4 + 2] + Sh[c4 + 2], 0.f);
                v.w = fmaxf(v.w * Sc[c4 + 3] + Sh[c4 + 3], 0.f);
            }
            ushort4 h;
            h.x = f2b(v.x); h.y = f2b(v.y); h.z = f2b(v.z); h.w = f2b(v.w);
            *(ushort4*)&As16[node * LDP + c4] = h;
        }
    }
    // stage B^T [128 j][128 k]
    if (fb) {
        for (int t = tid; t < 128 * 16; t += 256) {
            int k = t >> 4, j8 = (t & 15) << 3;
            bf16x8 v = *(const bf16x8*)((const u16*)W + k * 128 + j8);
            #pragma unroll
            for (int q = 0; q < 8; ++q) Bs16[(j8 + q) * LDP + k] = (u16)v[q];
        }
    } else {
        for (int t = tid; t < 128 * 32; t += 256) {
            int k = t >> 5, j4 = (t & 31) << 2;
            float4 v = *(const float4*)((const float*)W + k * 128 + j4);
            Bs16[(j4 + 0) * LDP + k] = f2b(v.x);
            Bs16[(j4 + 1) * LDP + k] = f2b(v.y);
            Bs16[(j4 + 2) * LDP + k] = f2b(v.z);
            Bs16[(j4 + 3) * LDP + k] = f2b(v.w);
        }
    }
    __syncthreads();

    int wv = tid >> 6, lane = tid & 63;
    int quad = lane >> 4, r = lane & 15;
    int m0 = wv * 16;
    f32x4 acc[8] = {{0.f,0.f,0.f,0.f},{0.f,0.f,0.f,0.f},{0.f,0.f,0.f,0.f},
                    {0.f,0.f,0.f,0.f},{0.f,0.f,0.f,0.f},{0.f,0.f,0.f,0.f},
                    {0.f,0.f,0.f,0.f},{0.f,0.f,0.f,0.f}};
    #pragma unroll
    for (int ks = 0; ks < 4; ++ks) {
        int ko = ks * 32 + quad * 8;
        bf16x8 af = *(const bf16x8*)&As16[(m0 + r) * LDP + ko];
        #pragma unroll
        for (int jt = 0; jt < 8; ++jt) {
            bf16x8 bfr = *(const bf16x8*)&Bs16[(jt * 16 + r) * LDP + ko];
            acc[jt] = __builtin_amdgcn_mfma_f32_16x16x32_bf16(af, bfr, acc[jt], 0, 0, 0);
        }
    }
    // epilogue: D(row=quad*4+reg, col=r per j-tile) -> LDS (As16 reused) -> 16B stores
    __syncthreads();   // all waves done reading As16/Bs16
    #pragma unroll
    for (int jt = 0; jt < 8; ++jt) {
        int j = jt * 16 + r;
        float bj = ldf(bi, j, fb);
        #pragma unroll
        for (int reg = 0; reg < 4; ++reg) {
            As16[(m0 + quad * 4 + reg) * LDP + j] = f2b(acc[jt][reg] + bj);
        }
    }
    __syncthreads();
    // 64 nodes * 16 groups of 8 cols = 1024 stores; 256 threads -> 4 reps
    #pragma unroll
    for (int rep = 0; rep < 4; ++rep) {
        int idx = rep * 256 + tid;
        int node = idx >> 4, c8 = (idx & 15) << 3;
        int n = n0 + node;
        if (n < N_NODES) {
            bf16x8 v = *(const bf16x8*)&As16[node * LDP + c8];
            *(bf16x8*)(dst + (size_t)n * 128 + c8) = v;
        }
    }
}

// ------ per-dst softmax aggregation: half-wave per edge (r10-proven, 66 us) ---
__global__ __launch_bounds__(64) void agg_kernel(const u16* __restrict__ XL,
        const u16* __restrict__ XR, const void* __restrict__ att,
        const int* __restrict__ fmt,
        const int* __restrict__ indptr, const int* __restrict__ srcs,
        float4* __restrict__ OUT4) {
    int lane = threadIdx.x;
    int n = blockIdx.x;
    int eh = lane >> 5, q = lane & 31;
    int fb = fmt[0];
    ushort4 xrv = *(const ushort4*)(XR + (size_t)n * 128 + q * 4);
    float xr0 = b2f(xrv.x), xr1 = b2f(xrv.y), xr2 = b2f(xrv.z), xr3 = b2f(xrv.w);
    float a0 = ldf(att, 4 * q,     fb);
    float a1 = ldf(att, 4 * q + 1, fb);
    float a2 = ldf(att, 4 * q + 2, fb);
    float a3 = ldf(att, 4 * q + 3, fb);
    int beg = indptr[n], end = indptr[n + 1];
    float acc0 = 0.f, acc1 = 0.f, acc2 = 0.f, acc3 = 0.f, dsum = 0.f;
    int nit = (end - beg + 1) >> 1;
    for (int it = 0; it < nit; ++it) {
        int i = beg + 2 * it + eh;
        bool valid = (i < end);
        int s = valid ? srcs[i] : 0;
        ushort4 xlv = *(const ushort4*)(XL + (size_t)s * 128 + q * 4);
        float x0 = b2f(xlv.x), x1 = b2f(xlv.y), x2 = b2f(xlv.z), x3 = b2f(xlv.w);
        float t0 = x0 + xr0; t0 = fmaxf(t0, 0.f) + NEG * fminf(t0, 0.f);
        float t1 = x1 + xr1; t1 = fmaxf(t1, 0.f) + NEG * fminf(t1, 0.f);
        float t2 = x2 + xr2; t2 = fmaxf(t2, 0.f) + NEG * fminf(t2, 0.f);
        float t3 = x3 + xr3; t3 = fmaxf(t3, 0.f) + NEG * fminf(t3, 0.f);
        float p = t0 * a0;
        p = fmaf(t1, a1, p); p = fmaf(t2, a2, p); p = fmaf(t3, a3, p);
        p += __shfl_xor(p, 1);
        p += __shfl_xor(p, 2);
        p += __shfl_xor(p, 4);
        p += __shfl_xor(p, 8);
        float w = valid ? __expf(fminf(p, 60.f)) : 0.f;
        acc0 = fmaf(w, x0, acc0); acc1 = fmaf(w, x1, acc1);
        acc2 = fmaf(w, x2, acc2); acc3 = fmaf(w, x3, acc3);
        dsum += w;
    }
    acc0 += __shfl_xor(acc0, 32);
    acc1 += __shfl_xor(acc1, 32);
    acc2 += __shfl_xor(acc2, 32);
    acc3 += __shfl_xor(acc3, 32);
    dsum += __shfl_xor(dsum, 32);
    if (eh == 0) {
        float inv = 1.f / (dsum + 1e-16f);
        float4 o; o.x = acc0 * inv; o.y = acc1 * inv; o.z = acc2 * inv; o.w = acc3 * inv;
        OUT4[(size_t)n * 32 + q] = o;
    }
}

// ---------------- GraphNorm stats: per-block partials (no atomics) ----------
__global__ __launch_bounds__(256) void colstats(const float* __restrict__ OUT,
        const void* __restrict__ bias, const int* __restrict__ fmt,
        float* __restrict__ Sp1, float* __restrict__ Sp2) {
    __shared__ float sh1[256], sh2[256];
    int tid = threadIdx.x;
    int c = tid & 127, half = tid >> 7;
    float bf = ldf(bias, c, fmt[0]);
    float s1 = 0.f, s2 = 0.f;
    for (int r = blockIdx.x * 2 + half; r < N_NODES; r += gridDim.x * 2) {
        float t = OUT[r * 128 + c] + bf;
        s1 += t; s2 += t * t;
    }
    sh1[tid] = s1; sh2[tid] = s2; __syncthreads();
    if (tid < 128) {
        Sp1[blockIdx.x * 128 + tid] = sh1[tid] + sh1[tid + 128];
        Sp2[blockIdx.x * 128 + tid] = sh2[tid] + sh2[tid + 128];
    }
}

__global__ void finalize_norm(const float* __restrict__ Sp1, const float* __restrict__ Sp2,
        const void* __restrict__ gamma, const void* __restrict__ beta,
        const void* __restrict__ msc, const void* __restrict__ bias,
        const int* __restrict__ fmt,
        float* __restrict__ scaleA, float* __restrict__ shiftB) {
    int c = threadIdx.x;
    if (c >= 128) return;
    float s1 = 0.f, s2 = 0.f;
    for (int b = 0; b < 256; ++b) {
        s1 += Sp1[b * 128 + c];
        s2 += Sp2[b * 128 + c];
    }
    int fb = fmt[0];
    const float invN = 1.f / (float)N_NODES;
    float mean = s1 * invN;
    float ex2  = s2 * invN;
    float ms = ldf(msc, c, fb);
    float var = ex2 - 2.f * ms * mean * mean + ms * ms * mean * mean;
    float rstd = rsqrtf(var + 1e-5f);
    float A = ldf(gamma, c, fb) * rstd;
    scaleA[c] = A;
    shiftB[c] = ldf(beta, c, fb) - A * (ms * mean - ldf(bias, c, fb));
}

// ---------------- fused MLP head with fused input norm+relu, fp32 out ---------
__global__ __launch_bounds__(256) void mlp_kernel(const float* __restrict__ H,
        const void* __restrict__ w1, const void* __restrict__ b1,
        const void* __restrict__ w2, const void* __restrict__ b2,
        const float* __restrict__ nscale, const float* __restrict__ nshift,
        const int* __restrict__ fmt,
        float* __restrict__ out) {
    __shared__ float W1s[128 * 64];
    __shared__ float W2s[128];
    __shared__ float b1s[64];
    __shared__ float Sc[128], Sh[128];
    int tid = threadIdx.x;
    int fb = fmt[0];
    if (fb) {
        for (int t = tid; t < 128 * 8; t += 256) {
            int row8 = t << 3;
            bf16x8 v = *(const bf16x8*)((const u16*)w1 + row8);
            #pragma unroll
            for (int q = 0; q < 8; ++q) W1s[row8 + q] = b2f((u16)v[q]);
        }
    } else {
        for (int t = tid; t < 128 * 64; t += 256) W1s[t] = ((const float*)w1)[t];
    }
    if (tid < 128) { W2s[tid] = ldf(w2, tid, fb); Sc[tid] = nscale[tid]; Sh[tid] = nshift[tid]; }
    if (tid < 64)  b1s[tid] = ldf(b1, tid, fb);
    __syncthreads();
    int n = blockIdx.x * 256 + tid;
    if (n >= N_NODES) return;
    float z[64];
    #pragma unroll
    for (int j = 0; j < 64; j++) z[j] = b1s[j];
    for (int kb = 0; kb < 128; kb += 16) {
        float h[16];
        #pragma unroll
        for (int t = 0; t < 4; t++) {
            float4 v = *(const float4*)&H[n * 128 + kb + t * 4];
            int c = kb + t * 4;
            h[4 * t]     = fmaxf(v.x * Sc[c]     + Sh[c],     0.f);
            h[4 * t + 1] = fmaxf(v.y * Sc[c + 1] + Sh[c + 1], 0.f);
            h[4 * t + 2] = fmaxf(v.z * Sc[c + 2] + Sh[c + 2], 0.f);
            h[4 * t + 3] = fmaxf(v.w * Sc[c + 3] + Sh[c + 3], 0.f);
        }
        #pragma unroll
        for (int i = 0; i < 16; i++) {
            float hv = h[i];
            const float* wrow = &W1s[(kb + i) * 64];
            #pragma unroll
            for (int j = 0; j < 64; j += 4) {
                const float4 w = *(const float4*)&wrow[j];
                z[j]     += hv * w.x;
                z[j + 1] += hv * w.y;
                z[j + 2] += hv * w.z;
                z[j + 3] += hv * w.w;
            }
        }
    }
    float o0 = ldf(b2, 0, fb), o1 = ldf(b2, 1, fb);
    #pragma unroll
    for (int j = 0; j < 64; j++) {
        float zr = fmaxf(z[j], 0.f);
        o0 += zr * W2s[j * 2];
        o1 += zr * W2s[j * 2 + 1];
    }
    if (o0 != o0) o0 = 12345.f;   // NaN canary
    if (o1 != o1) o1 = 12345.f;
    float2 o; o.x = o0; o.y = o1;
    ((float2*)out)[n] = o;
}

// ---------------- launch ----------------
extern "C" void kernel_launch(void* const* d_in, const int* in_sizes, int n_in,
                              void* d_out, int out_size, void* d_ws, size_t ws_size,
                              hipStream_t stream) {
    (void)in_sizes; (void)n_in; (void)out_size; (void)ws_size;
    const void* x    = d_in[0];
    const int*  ei   = (const int*)d_in[1];
    const void* Wl0  = d_in[2];
    const void* bl0  = d_in[3];
    const void* Wr0  = d_in[4];
    const void* br0  = d_in[5];
    const void* att0 = d_in[6];
    const void* bias0= d_in[7];
    const void* Wl1  = d_in[8];
    const void* bl1  = d_in[9];
    const void* Wr1  = d_in[10];
    const void* br1  = d_in[11];
    const void* att1 = d_in[12];
    const void* bias1= d_in[13];
    const void* g0   = d_in[14];
    const void* be0  = d_in[15];
    const void* ms0  = d_in[16];
    const void* g1   = d_in[17];
    const void* be1  = d_in[18];
    const void* ms1  = d_in[19];
    const void* W1   = d_in[20];
    const void* b1   = d_in[21];
    const void* W2   = d_in[22];
    const void* b2   = d_in[23];

    char* ws = (char*)d_ws;
    const size_t NF2 = (size_t)N_NODES * 128 * 2;
    const size_t NF4 = (size_t)N_NODES * 128 * 4;
    u16*   XLb = (u16*)(ws);
    u16*   XRb = (u16*)(ws + NF2);
    float* B2  = (float*)(ws + 2 * NF2);
    uint2* pairs = (uint2*)B2;            // 12.85 MB, aliased (dead before agg writes B2)
    char* small = ws + 2 * NF2 + NF4;     // 51.2 MB offset
    float* scaleA = (float*)(small + 1024);
    float* shiftB = (float*)(small + 1536);
    int*   flag   = (int*)(small + 2048);  // [0]=x bf16 [1]=0 [2]=i64 [3]=params bf16
    int*   bbase  = (int*)(small + 2112);  // 196 ints
    float* Sp1    = (float*)(small + 4096);            // 256*128 f = 128 KB
    float* Sp2    = (float*)(small + 4096 + 131072);   // 128 KB
    int*   bcnt   = (int*)(small + 4096 + 262144);     // 12544 ints
    int*   indptr = (int*)(small + 4096 + 262144 + 50176);
    int*   srcs   = indptr + (N_NODES + 64);
    // footprint ~55.1 MB (proven budget)

    const int* fX   = &flag[0];
    const int* fFP  = &flag[1];
    const int* fPar = &flag[3];

    init_all<<<(NCTR + 255) / 256, 256, 0, stream>>>((const u32*)x, (const u32*)Wl0,
                                                     ei, flag, bcnt);
    bin_a<<<(NE + 255) / 256, 256, 0, stream>>>(ei, flag, bcnt, pairs);
    bucket_scan<<<1, 256, 0, stream>>>(bcnt, bbase, indptr);
    bin_b<<<NBUCK, 256, 0, stream>>>(pairs, bcnt, bbase, indptr, srcs);

    dim3 ggemm((N_NODES + 63) / 64, 2);

    for (int layer = 0; layer < 2; ++layer) {
        const void* Wl = layer ? Wl1 : Wl0;  const void* bl = layer ? bl1 : bl0;
        const void* Wr = layer ? Wr1 : Wr0;  const void* br = layer ? br1 : br0;
        const void* at = layer ? att1 : att0;
        const void* bi = layer ? bias1 : bias0;
        const void* gm = layer ? g1 : g0;    const void* bt = layer ? be1 : be0;
        const void* mS = layer ? ms1 : ms0;
        const void* inp = layer ? (const void*)B2 : x;
        const int* fin  = layer ? fFP : fX;
        const float* ns = layer ? scaleA : nullptr;
        const float* nh = layer ? shiftB : nullptr;

        gemm_xf<<<ggemm, 256, 0, stream>>>(inp, fin, fPar, Wl, bl, Wr, br, ns, nh,
                                           XLb, XRb);
        agg_kernel<<<N_NODES, 64, 0, stream>>>(XLb, XRb, at, fPar, indptr, srcs,
                                               (float4*)B2);
        colstats<<<256, 256, 0, stream>>>(B2, bi, fPar, Sp1, Sp2);
        finalize_norm<<<1, 128, 0, stream>>>(Sp1, Sp2, gm, bt, mS, bi, fPar,
                                             scaleA, shiftB);
    }

    mlp_kernel<<<(N_NODES + 255) / 256, 256, 0, stream>>>(B2, W1, b1, W2, b2,
                                                          scaleA, shiftB, fPar,
                                                          (float*)d_out);
}

// Round 15
// 463.254 us; speedup vs baseline: 1.0884x; 1.0513x over previous
//
#include <hip/hip_runtime.h>
#include <hip/hip_bf16.h>

#define N_NODES 50000
#define NE      800000
#define NETOT   (NE + N_NODES)
#define NEG     0.2f
#define NBUCK   196      // ceil(50000/256) dst buckets
#define NSEG    64       // sub-counters per bucket (atomic-contention fix, r10-proven)
#define SEGCAP  128      // mean 63.8 + 8 sigma
#define NCTR    (NBUCK * NSEG)

typedef unsigned short u16;
typedef unsigned int   u32;
typedef __attribute__((ext_vector_type(8))) short bf16x8;
typedef __attribute__((ext_vector_type(4))) float f32x4;

__device__ __forceinline__ float b2f(u16 v) {
    union { float f; u32 u; } c; c.u = ((u32)v) << 16; return c.f;
}
__device__ __forceinline__ u16 f2b(float f) {
    union { float f; u32 u; } c; c.f = f;
    u32 r = c.u + 0x7FFF + ((c.u >> 16) & 1);
    return (u16)(r >> 16);
}
__device__ __forceinline__ float ldf(const void* p, int i, int fmt) {
    return fmt ? b2f(((const u16*)p)[i]) : ((const float*)p)[i];
}

// ---- fused init: format probes + i64 probe + bcnt zero ----
__global__ void init_all(const u32* __restrict__ xw, const u32* __restrict__ w0,
                         const int* __restrict__ ei,
                         int* __restrict__ flag, int* __restrict__ bcnt) {
    int g = blockIdx.x * 256 + threadIdx.x;
    if (g < NCTR) bcnt[g] = 0;
    if (blockIdx.x == 0) {
        int wv = threadIdx.x >> 6, l = threadIdx.x & 63;
        if (wv == 0) {          // x storage format -> flag[0]; flag[1]=0
            u32 v = xw[l * 50000 + 1];
            u32 e = (v >> 7) & 0xFF;
            unsigned long long m = __ballot(e >= 100 && e <= 140);
            if (l == 0) { flag[0] = (__popcll(m) >= 48) ? 1 : 0; flag[1] = 0; }
        } else if (wv == 1) {   // params family format -> flag[3]
            u32 v = w0[l * 128 + 1];
            u32 e = (v >> 7) & 0xFF;
            unsigned long long m = __ballot(e >= 100 && e <= 140);
            if (l == 0) flag[3] = (__popcll(m) >= 48) ? 1 : 0;
        } else if (wv == 2) {   // edge_index int64? -> flag[2]
            int v = ei[(l * 25000) | 1];
            unsigned long long nz = __ballot(v != 0);
            if (l == 0) flag[2] = (nz == 0ULL) ? 1 : 0;
        }
    }
}

// ---------------- binned CSR build (segmented counters, packed u32 pairs) -----
// pair word: ((d & 255) << 16) | s   (s < 50000 fits 16 bits; bucket = d >> 8)
__global__ void bin_a(const int* __restrict__ ei, const int* __restrict__ flag,
                      int* __restrict__ bcnt, u32* __restrict__ pairs) {
    int e = blockIdx.x * 256 + threadIdx.x;
    if (e >= NE) return;
    int f = flag[2];
    int s, d;
    if (f) { s = ei[2 * e]; d = ei[2 * (NE + e)]; }
    else   { s = ei[e];     d = ei[NE + e]; }
    int idx = (d >> 8) * NSEG + (blockIdx.x & (NSEG - 1));
    int pos = atomicAdd(&bcnt[idx], 1);
    if (pos < SEGCAP)
        pairs[(size_t)idx * SEGCAP + pos] = ((u32)(d & 255) << 16) | (u32)s;
}

__global__ void bucket_scan(const int* __restrict__ bcnt, int* __restrict__ bbase,
                            int* __restrict__ indptr) {
    __shared__ int sh[256];
    int tid = threadIdx.x;
    int tot = 0;
    if (tid < NBUCK) {
        int nb0 = tid << 8;
        int nodes = min(256, N_NODES - nb0);
        int edges = 0;
        for (int seg = 0; seg < NSEG; ++seg)
            edges += min(bcnt[tid * NSEG + seg], SEGCAP);
        tot = edges + nodes;
    }
    sh[tid] = tot; __syncthreads();
    for (int off = 1; off < 256; off <<= 1) {
        int u = (tid >= off) ? sh[tid - off] : 0;
        __syncthreads();
        sh[tid] += u;
        __syncthreads();
    }
    if (tid < NBUCK) bbase[tid] = sh[tid] - tot;
    if (tid == 0) indptr[N_NODES] = sh[NBUCK - 1];
}

__global__ __launch_bounds__(256) void bin_b(const u32* __restrict__ pairs,
        const int* __restrict__ bcnt, const int* __restrict__ bbase,
        int* __restrict__ indptr, int* __restrict__ srcs) {
    __shared__ int cnt[256];
    __shared__ int scn[256];
    __shared__ int msh[NSEG];
    int b = blockIdx.x, tid = threadIdx.x;
    int nb0 = b << 8;
    int nodesHere = min(256, N_NODES - nb0);
    if (tid < NSEG) msh[tid] = min(bcnt[b * NSEG + tid], SEGCAP);
    cnt[tid] = (tid < nodesHere) ? 1 : 0;   // self loop
    __syncthreads();
    const u32* bp = pairs + (size_t)b * NSEG * SEGCAP;
    for (int t = tid; t < NSEG * SEGCAP; t += 256) {
        int seg = t >> 7, i = t & (SEGCAP - 1);
        if (i < msh[seg]) {
            int dloc = (int)(bp[t] >> 16);
            atomicAdd(&cnt[dloc], 1);
        }
    }
    __syncthreads();
    int v = cnt[tid];
    scn[tid] = v; __syncthreads();
    for (int off = 1; off < 256; off <<= 1) {
        int u = (tid >= off) ? scn[tid - off] : 0;
        __syncthreads();
        scn[tid] += u;
        __syncthreads();
    }
    int myoff = bbase[b] + scn[tid] - v;
    if (tid < nodesHere) indptr[nb0 + tid] = myoff;
    __syncthreads();
    cnt[tid] = myoff;
    __syncthreads();
    if (tid < nodesHere) {
        int pos = atomicAdd(&cnt[tid], 1);
        srcs[pos] = nb0 + tid;
    }
    for (int t = tid; t < NSEG * SEGCAP; t += 256) {
        int seg = t >> 7, i = t & (SEGCAP - 1);
        if (i < msh[seg]) {
            u32 p = bp[t];
            int pos = atomicAdd(&cnt[p >> 16], 1);
            srcs[pos] = (int)(p & 0xffff);
        }
    }
}

// ------------- MFMA transform GEMM v3: grid.y=2, LDS-transposed epilogue ------
#define LDP 136
__global__ __launch_bounds__(256) void gemm_xf(const void* __restrict__ inp,
        const int* __restrict__ fin, const int* __restrict__ fw,
        const void* __restrict__ Wl, const void* __restrict__ bl,
        const void* __restrict__ Wr, const void* __restrict__ br,
        const float* __restrict__ nscale, const float* __restrict__ nshift,
        u16* __restrict__ XL, u16* __restrict__ XR) {
    __shared__ u16 As16[64 * LDP];    // A: [64 nodes][128 k]  (reused for output)
    __shared__ u16 Bs16[128 * LDP];   // B^T: [128 j][128 k]
    __shared__ float Sc[128], Sh[128];
    int fi = fin[0], fb = fw[0];
    int by = blockIdx.y;
    const void* W  = by ? Wr : Wl;
    const void* bi = by ? br : bl;
    u16* dst       = by ? XR : XL;
    int n0 = blockIdx.x * 64;
    int tid = threadIdx.x;
    bool donorm = (nscale != nullptr);
    if (donorm) {
        if (tid < 128) { Sc[tid] = nscale[tid]; Sh[tid] = nshift[tid]; }
        __syncthreads();
    }
    if (fi) {
        for (int t = tid; t < 64 * 16; t += 256) {
            int node = t >> 4, c8 = (t & 15) << 3;
            int n = n0 + node;
            bf16x8 v = {0,0,0,0,0,0,0,0};
            if (n < N_NODES) v = *(const bf16x8*)((const u16*)inp + (size_t)n * 128 + c8);
            *(bf16x8*)&As16[node * LDP + c8] = v;
        }
    } else {
        for (int t = tid; t < 64 * 32; t += 256) {
            int node = t >> 5, c4 = (t & 31) << 2;
            int n = n0 + node;
            float4 v = {0.f, 0.f, 0.f, 0.f};
            if (n < N_NODES) v = *(const float4*)((const float*)inp + (size_t)n * 128 + c4);
            if (donorm) {
                v.x = fmaxf(v.x * Sc[c4]     + Sh[c4],     0.f);
                v.y = fmaxf(v.y * Sc[c4 + 1] + Sh[c4 + 1], 0.f);
                v.z = fmaxf(v.z * Sc[c4 + 2] + Sh[c4 + 2], 0.f);
                v.w = fmaxf(v.w * Sc[c4 + 3] + Sh[c4 + 3], 0.f);
            }
            ushort4 h;
            h.x = f2b(v.x); h.y = f2b(v.y); h.z = f2b(v.z); h.w = f2b(v.w);
            *(ushort4*)&As16[node * LDP + c4] = h;
        }
    }
    if (fb) {
        for (int t = tid; t < 128 * 16; t += 256) {
            int k = t >> 4, j8 = (t & 15) << 3;
            bf16x8 v = *(const bf16x8*)((const u16*)W + k * 128 + j8);
            #pragma unroll
            for (int q = 0; q < 8; ++q) Bs16[(j8 + q) * LDP + k] = (u16)v[q];
        }
    } else {
        for (int t = tid; t < 128 * 32; t += 256) {
            int k = t >> 5, j4 = (t & 31) << 2;
            float4 v = *(const float4*)((const float*)W + k * 128 + j4);
            Bs16[(j4 + 0) * LDP + k] = f2b(v.x);
            Bs16[(j4 + 1) * LDP + k] = f2b(v.y);
            Bs16[(j4 + 2) * LDP + k] = f2b(v.z);
            Bs16[(j4 + 3) * LDP + k] = f2b(v.w);
        }
    }
    __syncthreads();

    int wv = tid >> 6, lane = tid & 63;
    int quad = lane >> 4, r = lane & 15;
    int m0 = wv * 16;
    f32x4 acc[8] = {{0.f,0.f,0.f,0.f},{0.f,0.f,0.f,0.f},{0.f,0.f,0.f,0.f},
                    {0.f,0.f,0.f,0.f},{0.f,0.f,0.f,0.f},{0.f,0.f,0.f,0.f},
                    {0.f,0.f,0.f,0.f},{0.f,0.f,0.f,0.f}};
    #pragma unroll
    for (int ks = 0; ks < 4; ++ks) {
        int ko = ks * 32 + quad * 8;
        bf16x8 af = *(const bf16x8*)&As16[(m0 + r) * LDP + ko];
        #pragma unroll
        for (int jt = 0; jt < 8; ++jt) {
            bf16x8 bfr = *(const bf16x8*)&Bs16[(jt * 16 + r) * LDP + ko];
            acc[jt] = __builtin_amdgcn_mfma_f32_16x16x32_bf16(af, bfr, acc[jt], 0, 0, 0);
        }
    }
    __syncthreads();   // all waves done reading As16/Bs16
    #pragma unroll
    for (int jt = 0; jt < 8; ++jt) {
        int j = jt * 16 + r;
        float bj = ldf(bi, j, fb);
        #pragma unroll
        for (int reg = 0; reg < 4; ++reg) {
            As16[(m0 + quad * 4 + reg) * LDP + j] = f2b(acc[jt][reg] + bj);
        }
    }
    __syncthreads();
    // 64 nodes * 16 groups of 8 cols = 1024 stores; 256 threads -> 4 reps
    #pragma unroll
    for (int rep = 0; rep < 4; ++rep) {
        int idx = rep * 256 + tid;
        int node = idx >> 4, c8 = (idx & 15) << 3;
        int n = n0 + node;
        if (n < N_NODES) {
            bf16x8 v = *(const bf16x8*)&As16[node * LDP + c8];
            *(bf16x8*)(dst + (size_t)n * 128 + c8) = v;
        }
    }
}

// ------ per-dst softmax aggregation: half-wave per edge, 2x unroll (4 MLP) ----
// lane q&31 owns channels 4q..4q+3; q<16 head0, q>=16 head1. Per iteration each
// half-wave processes edges beg+4*it+eh and beg+4*it+2+eh (2 chains in flight).
__global__ __launch_bounds__(64) void agg_kernel(const u16* __restrict__ XL,
        const u16* __restrict__ XR, const void* __restrict__ att,
        const int* __restrict__ fmt,
        const int* __restrict__ indptr, const int* __restrict__ srcs,
        float4* __restrict__ OUT4) {
    int lane = threadIdx.x;
    int n = blockIdx.x;
    int eh = lane >> 5, q = lane & 31;
    int fb = fmt[0];
    ushort4 xrv = *(const ushort4*)(XR + (size_t)n * 128 + q * 4);
    float xr0 = b2f(xrv.x), xr1 = b2f(xrv.y), xr2 = b2f(xrv.z), xr3 = b2f(xrv.w);
    float a0 = ldf(att, 4 * q,     fb);
    float a1 = ldf(att, 4 * q + 1, fb);
    float a2 = ldf(att, 4 * q + 2, fb);
    float a3 = ldf(att, 4 * q + 3, fb);
    int beg = indptr[n], end = indptr[n + 1];
    float acc0 = 0.f, acc1 = 0.f, acc2 = 0.f, acc3 = 0.f, dsum = 0.f;
    int nit = (end - beg + 3) >> 2;
    for (int it = 0; it < nit; ++it) {
        int iA = beg + 4 * it + eh;
        int iB = iA + 2;
        bool vA = (iA < end), vB = (iB < end);
        int sA = vA ? srcs[iA] : 0;
        int sB = vB ? srcs[iB] : 0;
        ushort4 xa = *(const ushort4*)(XL + (size_t)sA * 128 + q * 4);
        ushort4 xb = *(const ushort4*)(XL + (size_t)sB * 128 + q * 4);
        float A0 = b2f(xa.x), A1 = b2f(xa.y), A2 = b2f(xa.z), A3 = b2f(xa.w);
        float B0 = b2f(xb.x), B1 = b2f(xb.y), B2v = b2f(xb.z), B3 = b2f(xb.w);
        float tA0 = A0 + xr0; tA0 = fmaxf(tA0, 0.f) + NEG * fminf(tA0, 0.f);
        float tA1 = A1 + xr1; tA1 = fmaxf(tA1, 0.f) + NEG * fminf(tA1, 0.f);
        float tA2 = A2 + xr2; tA2 = fmaxf(tA2, 0.f) + NEG * fminf(tA2, 0.f);
        float tA3 = A3 + xr3; tA3 = fmaxf(tA3, 0.f) + NEG * fminf(tA3, 0.f);
        float tB0 = B0 + xr0; tB0 = fmaxf(tB0, 0.f) + NEG * fminf(tB0, 0.f);
        float tB1 = B1 + xr1; tB1 = fmaxf(tB1, 0.f) + NEG * fminf(tB1, 0.f);
        float tB2 = B2v + xr2; tB2 = fmaxf(tB2, 0.f) + NEG * fminf(tB2, 0.f);
        float tB3 = B3 + xr3; tB3 = fmaxf(tB3, 0.f) + NEG * fminf(tB3, 0.f);
        float pA = tA0 * a0;
        pA = fmaf(tA1, a1, pA); pA = fmaf(tA2, a2, pA); pA = fmaf(tA3, a3, pA);
        float pB = tB0 * a0;
        pB = fmaf(tB1, a1, pB); pB = fmaf(tB2, a2, pB); pB = fmaf(tB3, a3, pB);
        pA += __shfl_xor(pA, 1);  pB += __shfl_xor(pB, 1);
        pA += __shfl_xor(pA, 2);  pB += __shfl_xor(pB, 2);
        pA += __shfl_xor(pA, 4);  pB += __shfl_xor(pB, 4);
        pA += __shfl_xor(pA, 8);  pB += __shfl_xor(pB, 8);
        float wA = vA ? __expf(fminf(pA, 60.f)) : 0.f;
        float wB = vB ? __expf(fminf(pB, 60.f)) : 0.f;
        acc0 = fmaf(wA, A0, acc0); acc1 = fmaf(wA, A1, acc1);
        acc2 = fmaf(wA, A2, acc2); acc3 = fmaf(wA, A3, acc3);
        acc0 = fmaf(wB, B0, acc0); acc1 = fmaf(wB, B1, acc1);
        acc2 = fmaf(wB, B2v, acc2); acc3 = fmaf(wB, B3, acc3);
        dsum += wA + wB;
    }
    acc0 += __shfl_xor(acc0, 32);
    acc1 += __shfl_xor(acc1, 32);
    acc2 += __shfl_xor(acc2, 32);
    acc3 += __shfl_xor(acc3, 32);
    dsum += __shfl_xor(dsum, 32);
    if (eh == 0) {
        float inv = 1.f / (dsum + 1e-16f);
        float4 o; o.x = acc0 * inv; o.y = acc1 * inv; o.z = acc2 * inv; o.w = acc3 * inv;
        OUT4[(size_t)n * 32 + q] = o;
    }
}

// ---------------- GraphNorm stats: per-block partials (no atomics) ----------
__global__ __launch_bounds__(256) void colstats(const float* __restrict__ OUT,
        const void* __restrict__ bias, const int* __restrict__ fmt,
        float* __restrict__ Sp1, float* __restrict__ Sp2) {
    __shared__ float sh1[256], sh2[256];
    int tid = threadIdx.x;
    int c = tid & 127, half = tid >> 7;
    float bf = ldf(bias, c, fmt[0]);
    float s1 = 0.f, s2 = 0.f;
    for (int r = blockIdx.x * 2 + half; r < N_NODES; r += gridDim.x * 2) {
        float t = OUT[r * 128 + c] + bf;
        s1 += t; s2 += t * t;
    }
    sh1[tid] = s1; sh2[tid] = s2; __syncthreads();
    if (tid < 128) {
        Sp1[blockIdx.x * 128 + tid] = sh1[tid] + sh1[tid + 128];
        Sp2[blockIdx.x * 128 + tid] = sh2[tid] + sh2[tid + 128];
    }
}

__global__ void finalize_norm(const float* __restrict__ Sp1, const float* __restrict__ Sp2,
        const void* __restrict__ gamma, const void* __restrict__ beta,
        const void* __restrict__ msc, const void* __restrict__ bias,
        const int* __restrict__ fmt,
        float* __restrict__ scaleA, float* __restrict__ shiftB) {
    int c = threadIdx.x;
    if (c >= 128) return;
    float s1 = 0.f, s2 = 0.f;
    for (int b = 0; b < 256; ++b) {
        s1 += Sp1[b * 128 + c];
        s2 += Sp2[b * 128 + c];
    }
    int fb = fmt[0];
    const float invN = 1.f / (float)N_NODES;
    float mean = s1 * invN;
    float ex2  = s2 * invN;
    float ms = ldf(msc, c, fb);
    float var = ex2 - 2.f * ms * mean * mean + ms * ms * mean * mean;
    float rstd = rsqrtf(var + 1e-5f);
    float A = ldf(gamma, c, fb) * rstd;
    scaleA[c] = A;
    shiftB[c] = ldf(beta, c, fb) - A * (ms * mean - ldf(bias, c, fb));
}

// ---------------- fused MLP head with fused input norm+relu, fp32 out ---------
__global__ __launch_bounds__(256) void mlp_kernel(const float* __restrict__ H,
        const void* __restrict__ w1, const void* __restrict__ b1,
        const void* __restrict__ w2, const void* __restrict__ b2,
        const float* __restrict__ nscale, const float* __restrict__ nshift,
        const int* __restrict__ fmt,
        float* __restrict__ out) {
    __shared__ float W1s[128 * 64];
    __shared__ float W2s[128];
    __shared__ float b1s[64];
    __shared__ float Sc[128], Sh[128];
    int tid = threadIdx.x;
    int fb = fmt[0];
    if (fb) {
        for (int t = tid; t < 128 * 8; t += 256) {
            int row8 = t << 3;
            bf16x8 v = *(const bf16x8*)((const u16*)w1 + row8);
            #pragma unroll
            for (int q = 0; q < 8; ++q) W1s[row8 + q] = b2f((u16)v[q]);
        }
    } else {
        for (int t = tid; t < 128 * 64; t += 256) W1s[t] = ((const float*)w1)[t];
    }
    if (tid < 128) { W2s[tid] = ldf(w2, tid, fb); Sc[tid] = nscale[tid]; Sh[tid] = nshift[tid]; }
    if (tid < 64)  b1s[tid] = ldf(b1, tid, fb);
    __syncthreads();
    int n = blockIdx.x * 256 + tid;
    if (n >= N_NODES) return;
    float z[64];
    #pragma unroll
    for (int j = 0; j < 64; j++) z[j] = b1s[j];
    for (int kb = 0; kb < 128; kb += 16) {
        float h[16];
        #pragma unroll
        for (int t = 0; t < 4; t++) {
            float4 v = *(const float4*)&H[n * 128 + kb + t * 4];
            int c = kb + t * 4;
            h[4 * t]     = fmaxf(v.x * Sc[c]     + Sh[c],     0.f);
            h[4 * t + 1] = fmaxf(v.y * Sc[c + 1] + Sh[c + 1], 0.f);
            h[4 * t + 2] = fmaxf(v.z * Sc[c + 2] + Sh[c + 2], 0.f);
            h[4 * t + 3] = fmaxf(v.w * Sc[c + 3] + Sh[c + 3], 0.f);
        }
        #pragma unroll
        for (int i = 0; i < 16; i++) {
            float hv = h[i];
            const float* wrow = &W1s[(kb + i) * 64];
            #pragma unroll
            for (int j = 0; j < 64; j += 4) {
                const float4 w = *(const float4*)&wrow[j];
                z[j]     += hv * w.x;
                z[j + 1] += hv * w.y;
                z[j + 2] += hv * w.z;
                z[j + 3] += hv * w.w;
            }
        }
    }
    float o0 = ldf(b2, 0, fb), o1 = ldf(b2, 1, fb);
    #pragma unroll
    for (int j = 0; j < 64; j++) {
        float zr = fmaxf(z[j], 0.f);
        o0 += zr * W2s[j * 2];
        o1 += zr * W2s[j * 2 + 1];
    }
    if (o0 != o0) o0 = 12345.f;   // NaN canary
    if (o1 != o1) o1 = 12345.f;
    float2 o; o.x = o0; o.y = o1;
    ((float2*)out)[n] = o;
}

// ---------------- launch ----------------
extern "C" void kernel_launch(void* const* d_in, const int* in_sizes, int n_in,
                              void* d_out, int out_size, void* d_ws, size_t ws_size,
                              hipStream_t stream) {
    (void)in_sizes; (void)n_in; (void)out_size; (void)ws_size;
    const void* x    = d_in[0];
    const int*  ei   = (const int*)d_in[1];
    const void* Wl0  = d_in[2];
    const void* bl0  = d_in[3];
    const void* Wr0  = d_in[4];
    const void* br0  = d_in[5];
    const void* att0 = d_in[6];
    const void* bias0= d_in[7];
    const void* Wl1  = d_in[8];
    const void* bl1  = d_in[9];
    const void* Wr1  = d_in[10];
    const void* br1  = d_in[11];
    const void* att1 = d_in[12];
    const void* bias1= d_in[13];
    const void* g0   = d_in[14];
    const void* be0  = d_in[15];
    const void* ms0  = d_in[16];
    const void* g1   = d_in[17];
    const void* be1  = d_in[18];
    const void* ms1  = d_in[19];
    const void* W1   = d_in[20];
    const void* b1   = d_in[21];
    const void* W2   = d_in[22];
    const void* b2   = d_in[23];

    char* ws = (char*)d_ws;
    const size_t NF2 = (size_t)N_NODES * 128 * 2;
    const size_t NF4 = (size_t)N_NODES * 128 * 4;
    u16*   XLb = (u16*)(ws);
    u16*   XRb = (u16*)(ws + NF2);
    float* B2  = (float*)(ws + 2 * NF2);
    u32*   pairs = (u32*)B2;              // 6.4 MB, aliased (dead before agg writes B2)
    char* small = ws + 2 * NF2 + NF4;     // 51.2 MB offset
    float* scaleA = (float*)(small + 1024);
    float* shiftB = (float*)(small + 1536);
    int*   flag   = (int*)(small + 2048);  // [0]=x bf16 [1]=0 [2]=i64 [3]=params bf16
    int*   bbase  = (int*)(small + 2112);  // 196 ints
    float* Sp1    = (float*)(small + 4096);            // 256*128 f = 128 KB
    float* Sp2    = (float*)(small + 4096 + 131072);   // 128 KB
    int*   bcnt   = (int*)(small + 4096 + 262144);     // 12544 ints
    int*   indptr = (int*)(small + 4096 + 262144 + 50176);
    int*   srcs   = indptr + (N_NODES + 64);
    // footprint ~55.1 MB (proven budget)

    const int* fX   = &flag[0];
    const int* fFP  = &flag[1];
    const int* fPar = &flag[3];

    init_all<<<(NCTR + 255) / 256, 256, 0, stream>>>((const u32*)x, (const u32*)Wl0,
                                                     ei, flag, bcnt);
    bin_a<<<(NE + 255) / 256, 256, 0, stream>>>(ei, flag, bcnt, pairs);
    bucket_scan<<<1, 256, 0, stream>>>(bcnt, bbase, indptr);
    bin_b<<<NBUCK, 256, 0, stream>>>(pairs, bcnt, bbase, indptr, srcs);

    dim3 ggemm((N_NODES + 63) / 64, 2);

    for (int layer = 0; layer < 2; ++layer) {
        const void* Wl = layer ? Wl1 : Wl0;  const void* bl = layer ? bl1 : bl0;
        const void* Wr = layer ? Wr1 : Wr0;  const void* br = layer ? br1 : br0;
        const void* at = layer ? att1 : att0;
        const void* bi = layer ? bias1 : bias0;
        const void* gm = layer ? g1 : g0;    const void* bt = layer ? be1 : be0;
        const void* mS = layer ? ms1 : ms0;
        const void* inp = layer ? (const void*)B2 : x;
        const int* fin  = layer ? fFP : fX;
        const float* ns = layer ? scaleA : nullptr;
        const float* nh = layer ? shiftB : nullptr;

        gemm_xf<<<ggemm, 256, 0, stream>>>(inp, fin, fPar, Wl, bl, Wr, br, ns, nh,
                                           XLb, XRb);
        agg_kernel<<<N_NODES, 64, 0, stream>>>(XLb, XRb, at, fPar, indptr, srcs,
                                               (float4*)B2);
        colstats<<<256, 256, 0, stream>>>(B2, bi, fPar, Sp1, Sp2);
        finalize_norm<<<1, 128, 0, stream>>>(Sp1, Sp2, gm, bt, mS, bi, fPar,
                                             scaleA, shiftB);
    }

    mlp_kernel<<<(N_NODES + 255) / 256, 256, 0, stream>>>(B2, W1, b1, W2, b2,
                                                          scaleA, shiftB, fPar,
                                                          (float*)d_out);
}

// Round 16
// 452.621 us; speedup vs baseline: 1.1140x; 1.0235x over previous
//
#include <hip/hip_runtime.h>
#include <hip/hip_bf16.h>

#define N_NODES 50000
#define NE      800000
#define NETOT   (NE + N_NODES)
#define NEG     0.2f
#define NBUCK   196      // ceil(50000/256) dst buckets
#define NSEG    64       // sub-counters per bucket (atomic-contention fix, r10-proven)
#define SEGCAP  128      // mean 63.8 + 8 sigma
#define NCTR    (NBUCK * NSEG)

typedef unsigned short u16;
typedef unsigned int   u32;
typedef __attribute__((ext_vector_type(8))) short bf16x8;
typedef __attribute__((ext_vector_type(4))) float f32x4;

__device__ __forceinline__ float b2f(u16 v) {
    union { float f; u32 u; } c; c.u = ((u32)v) << 16; return c.f;
}
__device__ __forceinline__ u16 f2b(float f) {
    union { float f; u32 u; } c; c.f = f;
    u32 r = c.u + 0x7FFF + ((c.u >> 16) & 1);
    return (u16)(r >> 16);
}
__device__ __forceinline__ float ldf(const void* p, int i, int fmt) {
    return fmt ? b2f(((const u16*)p)[i]) : ((const float*)p)[i];
}

// ---- fused init: format probes + i64 probe + bcnt zero ----
__global__ void init_all(const u32* __restrict__ xw, const u32* __restrict__ w0,
                         const int* __restrict__ ei,
                         int* __restrict__ flag, int* __restrict__ bcnt) {
    int g = blockIdx.x * 256 + threadIdx.x;
    if (g < NCTR) bcnt[g] = 0;
    if (blockIdx.x == 0) {
        int wv = threadIdx.x >> 6, l = threadIdx.x & 63;
        if (wv == 0) {          // x storage format -> flag[0]; flag[1]=0
            u32 v = xw[l * 50000 + 1];
            u32 e = (v >> 7) & 0xFF;
            unsigned long long m = __ballot(e >= 100 && e <= 140);
            if (l == 0) { flag[0] = (__popcll(m) >= 48) ? 1 : 0; flag[1] = 0; }
        } else if (wv == 1) {   // params family format -> flag[3]
            u32 v = w0[l * 128 + 1];
            u32 e = (v >> 7) & 0xFF;
            unsigned long long m = __ballot(e >= 100 && e <= 140);
            if (l == 0) flag[3] = (__popcll(m) >= 48) ? 1 : 0;
        } else if (wv == 2) {   // edge_index int64? -> flag[2]
            int v = ei[(l * 25000) | 1];
            unsigned long long nz = __ballot(v != 0);
            if (l == 0) flag[2] = (nz == 0ULL) ? 1 : 0;
        }
    }
}

// ---------------- binned CSR build (segmented counters, packed u32 pairs) -----
// pair word: ((d & 255) << 16) | s   (s < 50000 fits 16 bits; bucket = d >> 8)
__global__ void bin_a(const int* __restrict__ ei, const int* __restrict__ flag,
                      int* __restrict__ bcnt, u32* __restrict__ pairs) {
    int e = blockIdx.x * 256 + threadIdx.x;
    if (e >= NE) return;
    int f = flag[2];
    int s, d;
    if (f) { s = ei[2 * e]; d = ei[2 * (NE + e)]; }
    else   { s = ei[e];     d = ei[NE + e]; }
    int idx = (d >> 8) * NSEG + (blockIdx.x & (NSEG - 1));
    int pos = atomicAdd(&bcnt[idx], 1);
    if (pos < SEGCAP)
        pairs[(size_t)idx * SEGCAP + pos] = ((u32)(d & 255) << 16) | (u32)s;
}

__global__ void bucket_scan(const int* __restrict__ bcnt, int* __restrict__ bbase,
                            int* __restrict__ indptr) {
    __shared__ int sh[256];
    int tid = threadIdx.x;
    int tot = 0;
    if (tid < NBUCK) {
        int nb0 = tid << 8;
        int nodes = min(256, N_NODES - nb0);
        int edges = 0;
        for (int seg = 0; seg < NSEG; ++seg)
            edges += min(bcnt[tid * NSEG + seg], SEGCAP);
        tot = edges + nodes;
    }
    sh[tid] = tot; __syncthreads();
    for (int off = 1; off < 256; off <<= 1) {
        int u = (tid >= off) ? sh[tid - off] : 0;
        __syncthreads();
        sh[tid] += u;
        __syncthreads();
    }
    if (tid < NBUCK) bbase[tid] = sh[tid] - tot;
    if (tid == 0) indptr[N_NODES] = sh[NBUCK - 1];
}

__global__ __launch_bounds__(256) void bin_b(const u32* __restrict__ pairs,
        const int* __restrict__ bcnt, const int* __restrict__ bbase,
        int* __restrict__ indptr, int* __restrict__ srcs) {
    __shared__ int cnt[256];
    __shared__ int scn[256];
    __shared__ int msh[NSEG];
    int b = blockIdx.x, tid = threadIdx.x;
    int nb0 = b << 8;
    int nodesHere = min(256, N_NODES - nb0);
    if (tid < NSEG) msh[tid] = min(bcnt[b * NSEG + tid], SEGCAP);
    cnt[tid] = (tid < nodesHere) ? 1 : 0;   // self loop
    __syncthreads();
    const u32* bp = pairs + (size_t)b * NSEG * SEGCAP;
    for (int t = tid; t < NSEG * SEGCAP; t += 256) {
        int seg = t >> 7, i = t & (SEGCAP - 1);
        if (i < msh[seg]) {
            int dloc = (int)(bp[t] >> 16);
            atomicAdd(&cnt[dloc], 1);
        }
    }
    __syncthreads();
    int v = cnt[tid];
    scn[tid] = v; __syncthreads();
    for (int off = 1; off < 256; off <<= 1) {
        int u = (tid >= off) ? scn[tid - off] : 0;
        __syncthreads();
        scn[tid] += u;
        __syncthreads();
    }
    int myoff = bbase[b] + scn[tid] - v;
    if (tid < nodesHere) indptr[nb0 + tid] = myoff;
    __syncthreads();
    cnt[tid] = myoff;
    __syncthreads();
    if (tid < nodesHere) {
        int pos = atomicAdd(&cnt[tid], 1);
        srcs[pos] = nb0 + tid;
    }
    for (int t = tid; t < NSEG * SEGCAP; t += 256) {
        int seg = t >> 7, i = t & (SEGCAP - 1);
        if (i < msh[seg]) {
            u32 p = bp[t];
            int pos = atomicAdd(&cnt[p >> 16], 1);
            srcs[pos] = (int)(p & 0xffff);
        }
    }
}

// ------------- MFMA transform GEMM v3: grid.y=2, LDS-transposed epilogue ------
#define LDP 136
__global__ __launch_bounds__(256) void gemm_xf(const void* __restrict__ inp,
        const int* __restrict__ fin, const int* __restrict__ fw,
        const void* __restrict__ Wl, const void* __restrict__ bl,
        const void* __restrict__ Wr, const void* __restrict__ br,
        const float* __restrict__ nscale, const float* __restrict__ nshift,
        u16* __restrict__ XL, u16* __restrict__ XR) {
    __shared__ u16 As16[64 * LDP];    // A: [64 nodes][128 k]  (reused for output)
    __shared__ u16 Bs16[128 * LDP];   // B^T: [128 j][128 k]
    __shared__ float Sc[128], Sh[128];
    int fi = fin[0], fb = fw[0];
    int by = blockIdx.y;
    const void* W  = by ? Wr : Wl;
    const void* bi = by ? br : bl;
    u16* dst       = by ? XR : XL;
    int n0 = blockIdx.x * 64;
    int tid = threadIdx.x;
    bool donorm = (nscale != nullptr);
    if (donorm) {
        if (tid < 128) { Sc[tid] = nscale[tid]; Sh[tid] = nshift[tid]; }
        __syncthreads();
    }
    if (fi) {
        for (int t = tid; t < 64 * 16; t += 256) {
            int node = t >> 4, c8 = (t & 15) << 3;
            int n = n0 + node;
            bf16x8 v = {0,0,0,0,0,0,0,0};
            if (n < N_NODES) v = *(const bf16x8*)((const u16*)inp + (size_t)n * 128 + c8);
            *(bf16x8*)&As16[node * LDP + c8] = v;
        }
    } else {
        for (int t = tid; t < 64 * 32; t += 256) {
            int node = t >> 5, c4 = (t & 31) << 2;
            int n = n0 + node;
            float4 v = {0.f, 0.f, 0.f, 0.f};
            if (n < N_NODES) v = *(const float4*)((const float*)inp + (size_t)n * 128 + c4);
            if (donorm) {
                v.x = fmaxf(v.x * Sc[c4]     + Sh[c4],     0.f);
                v.y = fmaxf(v.y * Sc[c4 + 1] + Sh[c4 + 1], 0.f);
                v.z = fmaxf(v.z * Sc[c4 + 2] + Sh[c4 + 2], 0.f);
                v.w = fmaxf(v.w * Sc[c4 + 3] + Sh[c4 + 3], 0.f);
            }
            ushort4 h;
            h.x = f2b(v.x); h.y = f2b(v.y); h.z = f2b(v.z); h.w = f2b(v.w);
            *(ushort4*)&As16[node * LDP + c4] = h;
        }
    }
    if (fb) {
        for (int t = tid; t < 128 * 16; t += 256) {
            int k = t >> 4, j8 = (t & 15) << 3;
            bf16x8 v = *(const bf16x8*)((const u16*)W + k * 128 + j8);
            #pragma unroll
            for (int q = 0; q < 8; ++q) Bs16[(j8 + q) * LDP + k] = (u16)v[q];
        }
    } else {
        for (int t = tid; t < 128 * 32; t += 256) {
            int k = t >> 5, j4 = (t & 31) << 2;
            float4 v = *(const float4*)((const float*)W + k * 128 + j4);
            Bs16[(j4 + 0) * LDP + k] = f2b(v.x);
            Bs16[(j4 + 1) * LDP + k] = f2b(v.y);
            Bs16[(j4 + 2) * LDP + k] = f2b(v.z);
            Bs16[(j4 + 3) * LDP + k] = f2b(v.w);
        }
    }
    __syncthreads();

    int wv = tid >> 6, lane = tid & 63;
    int quad = lane >> 4, r = lane & 15;
    int m0 = wv * 16;
    f32x4 acc[8] = {{0.f,0.f,0.f,0.f},{0.f,0.f,0.f,0.f},{0.f,0.f,0.f,0.f},
                    {0.f,0.f,0.f,0.f},{0.f,0.f,0.f,0.f},{0.f,0.f,0.f,0.f},
                    {0.f,0.f,0.f,0.f},{0.f,0.f,0.f,0.f}};
    #pragma unroll
    for (int ks = 0; ks < 4; ++ks) {
        int ko = ks * 32 + quad * 8;
        bf16x8 af = *(const bf16x8*)&As16[(m0 + r) * LDP + ko];
        #pragma unroll
        for (int jt = 0; jt < 8; ++jt) {
            bf16x8 bfr = *(const bf16x8*)&Bs16[(jt * 16 + r) * LDP + ko];
            acc[jt] = __builtin_amdgcn_mfma_f32_16x16x32_bf16(af, bfr, acc[jt], 0, 0, 0);
        }
    }
    __syncthreads();   // all waves done reading As16/Bs16
    #pragma unroll
    for (int jt = 0; jt < 8; ++jt) {
        int j = jt * 16 + r;
        float bj = ldf(bi, j, fb);
        #pragma unroll
        for (int reg = 0; reg < 4; ++reg) {
            As16[(m0 + quad * 4 + reg) * LDP + j] = f2b(acc[jt][reg] + bj);
        }
    }
    __syncthreads();
    // 64 nodes * 16 groups of 8 cols = 1024 stores; 256 threads -> 4 reps
    #pragma unroll
    for (int rep = 0; rep < 4; ++rep) {
        int idx = rep * 256 + tid;
        int node = idx >> 4, c8 = (idx & 15) << 3;
        int n = n0 + node;
        if (n < N_NODES) {
            bf16x8 v = *(const bf16x8*)&As16[node * LDP + c8];
            *(bf16x8*)(dst + (size_t)n * 128 + c8) = v;
        }
    }
}

// ------ per-dst softmax aggregation: half-wave per edge, 3x unroll (6 MLP) ----
// lane q&31 owns channels 4q..4q+3; q<16 head0, q>=16 head1. Per iteration each
// half-wave processes edges beg+6*it+{eh, eh+2, eh+4} (3 chains in flight).
__global__ __launch_bounds__(64) void agg_kernel(const u16* __restrict__ XL,
        const u16* __restrict__ XR, const void* __restrict__ att,
        const int* __restrict__ fmt,
        const int* __restrict__ indptr, const int* __restrict__ srcs,
        float4* __restrict__ OUT4) {
    int lane = threadIdx.x;
    int n = blockIdx.x;
    int eh = lane >> 5, q = lane & 31;
    int fb = fmt[0];
    ushort4 xrv = *(const ushort4*)(XR + (size_t)n * 128 + q * 4);
    float xr0 = b2f(xrv.x), xr1 = b2f(xrv.y), xr2 = b2f(xrv.z), xr3 = b2f(xrv.w);
    float a0 = ldf(att, 4 * q,     fb);
    float a1 = ldf(att, 4 * q + 1, fb);
    float a2 = ldf(att, 4 * q + 2, fb);
    float a3 = ldf(att, 4 * q + 3, fb);
    int beg = indptr[n], end = indptr[n + 1];
    float acc0 = 0.f, acc1 = 0.f, acc2 = 0.f, acc3 = 0.f, dsum = 0.f;
    int nit = (end - beg + 5) / 6;
    for (int it = 0; it < nit; ++it) {
        int iA = beg + 6 * it + eh;
        int iB = iA + 2;
        int iC = iA + 4;
        bool vA = (iA < end), vB = (iB < end), vC = (iC < end);
        int sA = vA ? srcs[iA] : 0;
        int sB = vB ? srcs[iB] : 0;
        int sC = vC ? srcs[iC] : 0;
        ushort4 xa = *(const ushort4*)(XL + (size_t)sA * 128 + q * 4);
        ushort4 xb = *(const ushort4*)(XL + (size_t)sB * 128 + q * 4);
        ushort4 xc = *(const ushort4*)(XL + (size_t)sC * 128 + q * 4);
        float A0 = b2f(xa.x), A1 = b2f(xa.y), A2 = b2f(xa.z), A3 = b2f(xa.w);
        float B0 = b2f(xb.x), B1 = b2f(xb.y), B2v = b2f(xb.z), B3 = b2f(xb.w);
        float C0 = b2f(xc.x), C1 = b2f(xc.y), C2 = b2f(xc.z), C3 = b2f(xc.w);
        float tA0 = A0 + xr0; tA0 = fmaxf(tA0, 0.f) + NEG * fminf(tA0, 0.f);
        float tA1 = A1 + xr1; tA1 = fmaxf(tA1, 0.f) + NEG * fminf(tA1, 0.f);
        float tA2 = A2 + xr2; tA2 = fmaxf(tA2, 0.f) + NEG * fminf(tA2, 0.f);
        float tA3 = A3 + xr3; tA3 = fmaxf(tA3, 0.f) + NEG * fminf(tA3, 0.f);
        float tB0 = B0 + xr0; tB0 = fmaxf(tB0, 0.f) + NEG * fminf(tB0, 0.f);
        float tB1 = B1 + xr1; tB1 = fmaxf(tB1, 0.f) + NEG * fminf(tB1, 0.f);
        float tB2 = B2v + xr2; tB2 = fmaxf(tB2, 0.f) + NEG * fminf(tB2, 0.f);
        float tB3 = B3 + xr3; tB3 = fmaxf(tB3, 0.f) + NEG * fminf(tB3, 0.f);
        float tC0 = C0 + xr0; tC0 = fmaxf(tC0, 0.f) + NEG * fminf(tC0, 0.f);
        float tC1 = C1 + xr1; tC1 = fmaxf(tC1, 0.f) + NEG * fminf(tC1, 0.f);
        float tC2 = C2 + xr2; tC2 = fmaxf(tC2, 0.f) + NEG * fminf(tC2, 0.f);
        float tC3 = C3 + xr3; tC3 = fmaxf(tC3, 0.f) + NEG * fminf(tC3, 0.f);
        float pA = tA0 * a0;
        pA = fmaf(tA1, a1, pA); pA = fmaf(tA2, a2, pA); pA = fmaf(tA3, a3, pA);
        float pB = tB0 * a0;
        pB = fmaf(tB1, a1, pB); pB = fmaf(tB2, a2, pB); pB = fmaf(tB3, a3, pB);
        float pC = tC0 * a0;
        pC = fmaf(tC1, a1, pC); pC = fmaf(tC2, a2, pC); pC = fmaf(tC3, a3, pC);
        pA += __shfl_xor(pA, 1);  pB += __shfl_xor(pB, 1);  pC += __shfl_xor(pC, 1);
        pA += __shfl_xor(pA, 2);  pB += __shfl_xor(pB, 2);  pC += __shfl_xor(pC, 2);
        pA += __shfl_xor(pA, 4);  pB += __shfl_xor(pB, 4);  pC += __shfl_xor(pC, 4);
        pA += __shfl_xor(pA, 8);  pB += __shfl_xor(pB, 8);  pC += __shfl_xor(pC, 8);
        float wA = vA ? __expf(fminf(pA, 60.f)) : 0.f;
        float wB = vB ? __expf(fminf(pB, 60.f)) : 0.f;
        float wC = vC ? __expf(fminf(pC, 60.f)) : 0.f;
        acc0 = fmaf(wA, A0, acc0); acc1 = fmaf(wA, A1, acc1);
        acc2 = fmaf(wA, A2, acc2); acc3 = fmaf(wA, A3, acc3);
        acc0 = fmaf(wB, B0, acc0); acc1 = fmaf(wB, B1, acc1);
        acc2 = fmaf(wB, B2v, acc2); acc3 = fmaf(wB, B3, acc3);
        acc0 = fmaf(wC, C0, acc0); acc1 = fmaf(wC, C1, acc1);
        acc2 = fmaf(wC, C2, acc2); acc3 = fmaf(wC, C3, acc3);
        dsum += wA + wB + wC;
    }
    acc0 += __shfl_xor(acc0, 32);
    acc1 += __shfl_xor(acc1, 32);
    acc2 += __shfl_xor(acc2, 32);
    acc3 += __shfl_xor(acc3, 32);
    dsum += __shfl_xor(dsum, 32);
    if (eh == 0) {
        float inv = 1.f / (dsum + 1e-16f);
        float4 o; o.x = acc0 * inv; o.y = acc1 * inv; o.z = acc2 * inv; o.w = acc3 * inv;
        OUT4[(size_t)n * 32 + q] = o;
    }
}

// ---------------- GraphNorm stats: per-block partials (no atomics) ----------
__global__ __launch_bounds__(256) void colstats(const float* __restrict__ OUT,
        const void* __restrict__ bias, const int* __restrict__ fmt,
        float* __restrict__ Sp1, float* __restrict__ Sp2) {
    __shared__ float sh1[256], sh2[256];
    int tid = threadIdx.x;
    int c = tid & 127, half = tid >> 7;
    float bf = ldf(bias, c, fmt[0]);
    float s1 = 0.f, s2 = 0.f;
    for (int r = blockIdx.x * 2 + half; r < N_NODES; r += gridDim.x * 2) {
        float t = OUT[r * 128 + c] + bf;
        s1 += t; s2 += t * t;
    }
    sh1[tid] = s1; sh2[tid] = s2; __syncthreads();
    if (tid < 128) {
        Sp1[blockIdx.x * 128 + tid] = sh1[tid] + sh1[tid + 128];
        Sp2[blockIdx.x * 128 + tid] = sh2[tid] + sh2[tid + 128];
    }
}

// parallel finalize: 128 blocks (one per channel), 256 threads reduce 256 partials
__global__ __launch_bounds__(256) void finalize_norm(const float* __restrict__ Sp1,
        const float* __restrict__ Sp2,
        const void* __restrict__ gamma, const void* __restrict__ beta,
        const void* __restrict__ msc, const void* __restrict__ bias,
        const int* __restrict__ fmt,
        float* __restrict__ scaleA, float* __restrict__ shiftB) {
    __shared__ float sh1[256], sh2[256];
    int c = blockIdx.x, tid = threadIdx.x;
    sh1[tid] = Sp1[tid * 128 + c];
    sh2[tid] = Sp2[tid * 128 + c];
    __syncthreads();
    for (int off = 128; off > 0; off >>= 1) {
        if (tid < off) { sh1[tid] += sh1[tid + off]; sh2[tid] += sh2[tid + off]; }
        __syncthreads();
    }
    if (tid == 0) {
        int fb = fmt[0];
        const float invN = 1.f / (float)N_NODES;
        float mean = sh1[0] * invN;
        float ex2  = sh2[0] * invN;
        float ms = ldf(msc, c, fb);
        float var = ex2 - 2.f * ms * mean * mean + ms * ms * mean * mean;
        float rstd = rsqrtf(var + 1e-5f);
        float A = ldf(gamma, c, fb) * rstd;
        scaleA[c] = A;
        shiftB[c] = ldf(beta, c, fb) - A * (ms * mean - ldf(bias, c, fb));
    }
}

// ---------------- fused MLP head with fused input norm+relu, fp32 out ---------
__global__ __launch_bounds__(256) void mlp_kernel(const float* __restrict__ H,
        const void* __restrict__ w1, const void* __restrict__ b1,
        const void* __restrict__ w2, const void* __restrict__ b2,
        const float* __restrict__ nscale, const float* __restrict__ nshift,
        const int* __restrict__ fmt,
        float* __restrict__ out) {
    __shared__ float W1s[128 * 64];
    __shared__ float W2s[128];
    __shared__ float b1s[64];
    __shared__ float Sc[128], Sh[128];
    int tid = threadIdx.x;
    int fb = fmt[0];
    if (fb) {
        for (int t = tid; t < 128 * 8; t += 256) {
            int row8 = t << 3;
            bf16x8 v = *(const bf16x8*)((const u16*)w1 + row8);
            #pragma unroll
            for (int q = 0; q < 8; ++q) W1s[row8 + q] = b2f((u16)v[q]);
        }
    } else {
        for (int t = tid; t < 128 * 64; t += 256) W1s[t] = ((const float*)w1)[t];
    }
    if (tid < 128) { W2s[tid] = ldf(w2, tid, fb); Sc[tid] = nscale[tid]; Sh[tid] = nshift[tid]; }
    if (tid < 64)  b1s[tid] = ldf(b1, tid, fb);
    __syncthreads();
    int n = blockIdx.x * 256 + tid;
    if (n >= N_NODES) return;
    float z[64];
    #pragma unroll
    for (int j = 0; j < 64; j++) z[j] = b1s[j];
    for (int kb = 0; kb < 128; kb += 16) {
        float h[16];
        #pragma unroll
        for (int t = 0; t < 4; t++) {
            float4 v = *(const float4*)&H[n * 128 + kb + t * 4];
            int c = kb + t * 4;
            h[4 * t]     = fmaxf(v.x * Sc[c]     + Sh[c],     0.f);
            h[4 * t + 1] = fmaxf(v.y * Sc[c + 1] + Sh[c + 1], 0.f);
            h[4 * t + 2] = fmaxf(v.z * Sc[c + 2] + Sh[c + 2], 0.f);
            h[4 * t + 3] = fmaxf(v.w * Sc[c + 3] + Sh[c + 3], 0.f);
        }
        #pragma unroll
        for (int i = 0; i < 16; i++) {
            float hv = h[i];
            const float* wrow = &W1s[(kb + i) * 64];
            #pragma unroll
            for (int j = 0; j < 64; j += 4) {
                const float4 w = *(const float4*)&wrow[j];
                z[j]     += hv * w.x;
                z[j + 1] += hv * w.y;
                z[j + 2] += hv * w.z;
                z[j + 3] += hv * w.w;
            }
        }
    }
    float o0 = ldf(b2, 0, fb), o1 = ldf(b2, 1, fb);
    #pragma unroll
    for (int j = 0; j < 64; j++) {
        float zr = fmaxf(z[j], 0.f);
        o0 += zr * W2s[j * 2];
        o1 += zr * W2s[j * 2 + 1];
    }
    if (o0 != o0) o0 = 12345.f;   // NaN canary
    if (o1 != o1) o1 = 12345.f;
    float2 o; o.x = o0; o.y = o1;
    ((float2*)out)[n] = o;
}

// ---------------- launch ----------------
extern "C" void kernel_launch(void* const* d_in, const int* in_sizes, int n_in,
                              void* d_out, int out_size, void* d_ws, size_t ws_size,
                              hipStream_t stream) {
    (void)in_sizes; (void)n_in; (void)out_size; (void)ws_size;
    const void* x    = d_in[0];
    const int*  ei   = (const int*)d_in[1];
    const void* Wl0  = d_in[2];
    const void* bl0  = d_in[3];
    const void* Wr0  = d_in[4];
    const void* br0  = d_in[5];
    const void* att0 = d_in[6];
    const void* bias0= d_in[7];
    const void* Wl1  = d_in[8];
    const void* bl1  = d_in[9];
    const void* Wr1  = d_in[10];
    const void* br1  = d_in[11];
    const void* att1 = d_in[12];
    const void* bias1= d_in[13];
    const void* g0   = d_in[14];
    const void* be0  = d_in[15];
    const void* ms0  = d_in[16];
    const void* g1   = d_in[17];
    const void* be1  = d_in[18];
    const void* ms1  = d_in[19];
    const void* W1   = d_in[20];
    const void* b1   = d_in[21];
    const void* W2   = d_in[22];
    const void* b2   = d_in[23];

    char* ws = (char*)d_ws;
    const size_t NF2 = (size_t)N_NODES * 128 * 2;
    const size_t NF4 = (size_t)N_NODES * 128 * 4;
    u16*   XLb = (u16*)(ws);
    u16*   XRb = (u16*)(ws + NF2);
    float* B2  = (float*)(ws + 2 * NF2);
    u32*   pairs = (u32*)B2;              // 6.4 MB, aliased (dead before agg writes B2)
    char* small = ws + 2 * NF2 + NF4;     // 51.2 MB offset
    float* scaleA = (float*)(small + 1024);
    float* shiftB = (float*)(small + 1536);
    int*   flag   = (int*)(small + 2048);  // [0]=x bf16 [1]=0 [2]=i64 [3]=params bf16
    int*   bbase  = (int*)(small + 2112);  // 196 ints
    float* Sp1    = (float*)(small + 4096);            // 256*128 f = 128 KB
    float* Sp2    = (float*)(small + 4096 + 131072);   // 128 KB
    int*   bcnt   = (int*)(small + 4096 + 262144);     // 12544 ints
    int*   indptr = (int*)(small + 4096 + 262144 + 50176);
    int*   srcs   = indptr + (N_NODES + 64);
    // footprint ~55.1 MB (proven budget)

    const int* fX   = &flag[0];
    const int* fFP  = &flag[1];
    const int* fPar = &flag[3];

    init_all<<<(NCTR + 255) / 256, 256, 0, stream>>>((const u32*)x, (const u32*)Wl0,
                                                     ei, flag, bcnt);
    bin_a<<<(NE + 255) / 256, 256, 0, stream>>>(ei, flag, bcnt, pairs);
    bucket_scan<<<1, 256, 0, stream>>>(bcnt, bbase, indptr);
    bin_b<<<NBUCK, 256, 0, stream>>>(pairs, bcnt, bbase, indptr, srcs);

    dim3 ggemm((N_NODES + 63) / 64, 2);

    for (int layer = 0; layer < 2; ++layer) {
        const void* Wl = layer ? Wl1 : Wl0;  const void* bl = layer ? bl1 : bl0;
        const void* Wr = layer ? Wr1 : Wr0;  const void* br = layer ? br1 : br0;
        const void* at = layer ? att1 : att0;
        const void* bi = layer ? bias1 : bias0;
        const void* gm = layer ? g1 : g0;    const void* bt = layer ? be1 : be0;
        const void* mS = layer ? ms1 : ms0;
        const void* inp = layer ? (const void*)B2 : x;
        const int* fin  = layer ? fFP : fX;
        const float* ns = layer ? scaleA : nullptr;
        const float* nh = layer ? shiftB : nullptr;

        gemm_xf<<<ggemm, 256, 0, stream>>>(inp, fin, fPar, Wl, bl, Wr, br, ns, nh,
                                           XLb, XRb);
        agg_kernel<<<N_NODES, 64, 0, stream>>>(XLb, XRb, at, fPar, indptr, srcs,
                                               (float4*)B2);
        colstats<<<256, 256, 0, stream>>>(B2, bi, fPar, Sp1, Sp2);
        finalize_norm<<<128, 256, 0, stream>>>(Sp1, Sp2, gm, bt, mS, bi, fPar,
                                               scaleA, shiftB);
    }

    mlp_kernel<<<(N_NODES + 255) / 256, 256, 0, stream>>>(B2, W1, b1, W2, b2,
                                                          scaleA, shiftB, fPar,
                                                          (float*)d_out);
}